// Round 16
// baseline (147.398 us; speedup 1.0000x reference)
//
#include <hip/hip_runtime.h>
#include <hip/hip_bf16.h>

#define NN 50000
#define EE 800000
#define IN_F 128
#define HC 64
#define NEG_SLOPE 0.2f
#define BN_EPS 1e-5f

#define NBKT 196          // buckets of 256 nodes: dst>>8 (max 49999>>8 = 195)
#define NBLKS 200         // sort blocks
#define EPB2 (EE / NBLKS) // 4000 edges per sort block
#define TOTH (NBKT * NBLKS)  // 39200
#define NODE_GRID 2048    // node kernel grid (grid-stride over NN/4 groups)

typedef __attribute__((ext_vector_type(8))) short short8;
typedef __attribute__((ext_vector_type(4))) float f32x4;

__device__ __forceinline__ ushort f2bf(float f) {
  uint u = __float_as_uint(f);
  uint r = u + 0x7FFF + ((u >> 16) & 1);   // RNE
  return (ushort)(r >> 16);
}
__device__ __forceinline__ float bf2f(ushort u) {
  return __uint_as_float(((uint)u) << 16);
}

// ---------------- Kernel 1: MFMA bf16 GEMM: h=x@W (bf16), res=x@Wres (bf16), al_s, al_d --
__global__ __launch_bounds__(256) void gemm_mfma_kernel(
    const float* __restrict__ x, const float* __restrict__ W, const float* __restrict__ Wres,
    const float* __restrict__ a_src, const float* __restrict__ a_dst,
    ushort* __restrict__ h, ushort* __restrict__ res,
    float* __restrict__ al_s, float* __restrict__ al_d) {
  __shared__ ushort bs[128 * 128];   // [col][k] bf16, swizzled: byte ^= (col&7)<<4
  __shared__ ushort xs[64 * 128];    // [row][k] bf16, swizzled: byte ^= (row&7)<<4

  const int tid = threadIdx.x;
  const int r0 = blockIdx.x * 64;

  {
    const int c4 = (tid & 31) * 4;
    const int kb = (tid >> 5) * 16;
    const float* src0 = (c4 < HC) ? (W + c4) : (Wres + (c4 - HC));
    char* base = (char*)bs;
#pragma unroll
    for (int j = 0; j < 8; ++j) {
      int k0 = kb + j * 2;
      float4 fa = *(const float4*)(src0 + (size_t)k0 * HC);
      float4 fb = *(const float4*)(src0 + (size_t)(k0 + 1) * HC);
      uint p0 = (uint)f2bf(fa.x) | ((uint)f2bf(fb.x) << 16);
      uint p1 = (uint)f2bf(fa.y) | ((uint)f2bf(fb.y) << 16);
      uint p2 = (uint)f2bf(fa.z) | ((uint)f2bf(fb.z) << 16);
      uint p3 = (uint)f2bf(fa.w) | ((uint)f2bf(fb.w) << 16);
      *(uint*)(base + (((c4 + 0) * 256 + k0 * 2) ^ (((c4 + 0) & 7) << 4))) = p0;
      *(uint*)(base + (((c4 + 1) * 256 + k0 * 2) ^ (((c4 + 1) & 7) << 4))) = p1;
      *(uint*)(base + (((c4 + 2) * 256 + k0 * 2) ^ (((c4 + 2) & 7) << 4))) = p2;
      *(uint*)(base + (((c4 + 3) * 256 + k0 * 2) ^ (((c4 + 3) & 7) << 4))) = p3;
    }
  }
  {
    char* base = (char*)xs;
#pragma unroll
    for (int i = 0; i < 8; ++i) {
      int f4 = i * 256 + tid;
      int row = f4 >> 5;
      int kq = (f4 & 31) * 4;
      int gr = r0 + row;
      float4 v = make_float4(0.f, 0.f, 0.f, 0.f);
      if (gr < NN) v = *(const float4*)(x + (size_t)gr * IN_F + kq);
      uint lo = (uint)f2bf(v.x) | ((uint)f2bf(v.y) << 16);
      uint hi = (uint)f2bf(v.z) | ((uint)f2bf(v.w) << 16);
      uint off = (uint)((row * 256 + kq * 2) ^ ((row & 7) << 4));
      *(uint2*)(base + off) = make_uint2(lo, hi);
    }
  }
  __syncthreads();

  const int w = tid >> 6;
  const int l = tid & 63;
  const int lr = l & 15;
  const int lk = (l >> 4) * 8;

  f32x4 acc[8];
#pragma unroll
  for (int i = 0; i < 8; ++i) acc[i] = (f32x4){0.f, 0.f, 0.f, 0.f};

  const char* xb = (const char*)xs;
  const char* bb = (const char*)bs;
  const int arow = w * 16 + lr;
#pragma unroll
  for (int ks = 0; ks < 4; ++ks) {
    const int kbase = ks * 32 + lk;
    short8 af = *(const short8*)(xb + ((arow * 256 + kbase * 2) ^ ((arow & 7) << 4)));
#pragma unroll
    for (int ct = 0; ct < 8; ++ct) {
      const int c = ct * 16 + lr;
      short8 bfr = *(const short8*)(bb + ((c * 256 + kbase * 2) ^ ((c & 7) << 4)));
      acc[ct] = __builtin_amdgcn_mfma_f32_16x16x32_bf16(af, bfr, acc[ct], 0, 0, 0);
    }
  }

  const int rb = r0 + w * 16;
#pragma unroll
  for (int ct = 0; ct < 8; ++ct) {
#pragma unroll
    for (int r = 0; r < 4; ++r) {
      int gr = rb + (l >> 4) * 4 + r;
      if (gr < NN) {
        if (ct < 4) h[(size_t)gr * HC + ct * 16 + lr] = f2bf(acc[ct][r]);
        else        res[(size_t)gr * HC + (ct - 4) * 16 + lr] = f2bf(acc[ct][r]);
      }
    }
  }

  float myS[4] = {0.f, 0.f, 0.f, 0.f};
  float myD[4] = {0.f, 0.f, 0.f, 0.f};
#pragma unroll
  for (int ct = 0; ct < 4; ++ct) {
    float asv = a_src[ct * 16 + lr];
    float adv = a_dst[ct * 16 + lr];
#pragma unroll
    for (int r = 0; r < 4; ++r) {
      float ps = acc[ct][r] * asv;
      float pd = acc[ct][r] * adv;
      ps += __shfl_xor(ps, 1); ps += __shfl_xor(ps, 2); ps += __shfl_xor(ps, 4); ps += __shfl_xor(ps, 8);
      pd += __shfl_xor(pd, 1); pd += __shfl_xor(pd, 2); pd += __shfl_xor(pd, 4); pd += __shfl_xor(pd, 8);
      if (lr == ct) { myS[r] = ps; myD[r] = pd; }
    }
  }
  if (lr < 4) {
#pragma unroll
    for (int r = 0; r < 4; ++r) {
      int gr = rb + (l >> 4) * 4 + r;
      if (gr < NN) {
        al_s[gr * 4 + lr] = myS[r];
        al_d[gr * 4 + lr] = myD[r];
      }
    }
  }
}

// ---------------- Kernel 2: per-block bucket histogram, int4-vectorized ----------------
__global__ __launch_bounds__(256) void histB_kernel(const int* __restrict__ dst,
                                                    int* __restrict__ histmat,
                                                    float* __restrict__ sums) {
  __shared__ int lh[NBKT];
  const int tid = threadIdx.x;
  if (blockIdx.x == 0 && tid < 32)
    ((float4*)sums)[tid] = make_float4(0.f, 0.f, 0.f, 0.f);   // 128 floats
  for (int i = tid; i < NBKT; i += 256) lh[i] = 0;
  __syncthreads();
  const int4* d4 = (const int4*)(dst + blockIdx.x * EPB2);
  for (int p = tid; p < EPB2 / 4; p += 256) {
    int4 d = d4[p];
    atomicAdd(&lh[d.x >> 8], 1);
    atomicAdd(&lh[d.y >> 8], 1);
    atomicAdd(&lh[d.z >> 8], 1);
    atomicAdd(&lh[d.w >> 8], 1);
  }
  __syncthreads();
  for (int i = tid; i < NBKT; i += 256) histmat[i * NBLKS + blockIdx.x] = lh[i];
}

// ---------------- Kernel 3: per-bucket absolute bases (196 independent blocks) ---------
__global__ __launch_bounds__(256) void scanB_kernel(const int* __restrict__ histmat,
                                                    int* __restrict__ histabs,
                                                    int* __restrict__ bucket_base) {
  const int b = blockIdx.x;
  const int t = threadIdx.x;
  const int lane = t & 63;
  const int wv = t >> 6;
  int part = 0;
  for (int i = t; i < b * NBLKS; i += 256) part += histmat[i];
#pragma unroll
  for (int off = 1; off < 64; off <<= 1) part += __shfl_xor(part, off);
  __shared__ int ws1[4];
  if (lane == 0) ws1[wv] = part;
  __syncthreads();
  const int prefix = ws1[0] + ws1[1] + ws1[2] + ws1[3];
  int v = (t < NBLKS) ? histmat[b * NBLKS + t] : 0;
  int incl = v;
#pragma unroll
  for (int off = 1; off < 64; off <<= 1) {
    int tt = __shfl_up(incl, off);
    if (lane >= off) incl += tt;
  }
  __shared__ int ws2[4];
  if (lane == 63) ws2[wv] = incl;
  __syncthreads();
  int woff = 0;
  for (int w = 0; w < wv; ++w) woff += ws2[w];
  if (t < NBLKS) histabs[b * NBLKS + t] = prefix + woff + incl - v;
  if (t == 0) bucket_base[b] = prefix;
  if (b == NBKT - 1 && t == 0) bucket_base[NBKT] = EE;
}

// ---------------- Kernel 4: place edges into bucket-sorted pairs (int4 loads) ----------
__global__ __launch_bounds__(256) void placeB_kernel(const int* __restrict__ src,
                                                     const int* __restrict__ dst,
                                                     const int* __restrict__ histabs,
                                                     uint* __restrict__ pairs) {
  __shared__ int cur[NBKT];
  const int tid = threadIdx.x;
  for (int i = tid; i < NBKT; i += 256) cur[i] = histabs[i * NBLKS + blockIdx.x];
  __syncthreads();
  const int4* s4 = (const int4*)(src + blockIdx.x * EPB2);
  const int4* d4 = (const int4*)(dst + blockIdx.x * EPB2);
  for (int p = tid; p < EPB2 / 4; p += 256) {
    int4 d = d4[p];
    int4 s = s4[p];
    int q;
    q = atomicAdd(&cur[d.x >> 8], 1); pairs[q] = ((uint)(d.x & 255) << 16) | (uint)s.x;
    q = atomicAdd(&cur[d.y >> 8], 1); pairs[q] = ((uint)(d.y & 255) << 16) | (uint)s.y;
    q = atomicAdd(&cur[d.z >> 8], 1); pairs[q] = ((uint)(d.z & 255) << 16) | (uint)s.z;
    q = atomicAdd(&cur[d.w >> 8], 1); pairs[q] = ((uint)(d.w & 255) << 16) | (uint)s.w;
  }
}

// ---------------- Kernel 5: fine scatter; derives row_ptr locally ----------------
__global__ __launch_bounds__(256) void bscatter_kernel(const uint* __restrict__ pairs,
                                                       const int* __restrict__ bucket_base,
                                                       int* __restrict__ row_ptr,
                                                       int* __restrict__ col) {
  __shared__ int cnt[256];
  __shared__ int wsum[4];
  const int b = blockIdx.x;
  const int tid = threadIdx.x;
  cnt[tid] = 0;
  __syncthreads();
  const int lo = bucket_base[b];
  const int hi = bucket_base[b + 1];
  for (int i = lo + tid; i < hi; i += 256)
    atomicAdd(&cnt[(pairs[i] >> 16) & 255], 1);
  __syncthreads();
  const int lane = tid & 63;
  const int wv = tid >> 6;
  const int v = cnt[tid];
  int incl = v;
#pragma unroll
  for (int off = 1; off < 64; off <<= 1) {
    int t = __shfl_up(incl, off);
    if (lane >= off) incl += t;
  }
  if (lane == 63) wsum[wv] = incl;
  __syncthreads();
  int woff = 0;
  for (int w = 0; w < wv; ++w) woff += wsum[w];
  const int excl = lo + woff + incl - v;
  __syncthreads();
  cnt[tid] = excl;                     // reuse as cursor
  const int node = (b << 8) + tid;
  if (node < NN) row_ptr[node] = excl;
  if (b == NBKT - 1 && tid == 255) row_ptr[NN] = EE;
  __syncthreads();
  for (int i = lo + tid; i < hi; i += 256) {
    uint u = pairs[i];
    int d = (u >> 16) & 255;
    int p = atomicAdd(&cnt[d], 1);
    col[p] = (int)(u & 0xFFFFu);
  }
}

// ---------------- Kernel 6: per-node aggregate (R14 inner loop) + fused BN stats -------
// Grid-stride over node groups; per-thread val/val^2 partials -> block LDS reduce ->
// 128 atomics/block (2048 blocks -> 262K atomics, uncontended). Deletes stats kernel.
__global__ __launch_bounds__(256) void node_kernel(
    const ushort* __restrict__ h, const float* __restrict__ al_s, const float* __restrict__ al_d,
    const int* __restrict__ row_ptr, const int* __restrict__ col,
    ushort* __restrict__ out_pre, float* __restrict__ sums) {
  const int tid = threadIdx.x;
  const int lane = tid & 63;
  const int wv6 = tid >> 6;
  const int head = lane >> 4;       // phase-B head (channel group)
  const int hdA = lane & 3;         // phase-A head
  const int elA = lane >> 2;        // phase-A edge slot (0..15)

  float sacc = 0.f, sacc2 = 0.f;

  for (int grp = blockIdx.x; grp < NN / 4; grp += NODE_GRID) {
    const int node = grp * 4 + wv6;
    const float aldB = al_d[(uint)node * 4u + head];
    const float aldA = al_d[(uint)node * 4u + hdA];

    float e0 = al_s[(uint)node * 4u + head] + aldB;   // self loop
    e0 = e0 > 0.f ? e0 : NEG_SLOPE * e0;
    float m = __expf(e0);
    float denom = m;
    float acc = m * bf2f(h[((uint)node << 6) + lane]);

    const int beg = row_ptr[node];
    const int end = row_ptr[node + 1];
    for (int idx = beg; idx < end; idx += 16) {
      // phase A: one (edge, head) numerator per lane; 0 for tail slots
      const int j = idx + elA;
      const uint sA = (uint)col[j < end ? j : beg];
      float ee = al_s[sA * 4u + hdA] + aldA;
      ee = ee > 0.f ? ee : NEG_SLOPE * ee;
      const float mmA = (j < end) ? __expf(ee) : 0.f;
      // phase B: flat, branch-free
      uint ss[16];
#pragma unroll
      for (int e = 0; e < 16; ++e) ss[e] = (uint)__shfl((int)sA, e * 4);
      float hv[16];
#pragma unroll
      for (int e = 0; e < 16; ++e) hv[e] = bf2f(h[(ss[e] << 6) + lane]);
      float mm[16];
#pragma unroll
      for (int e = 0; e < 16; ++e) mm[e] = __shfl(mmA, e * 4 + head);
#pragma unroll
      for (int e = 0; e < 16; ++e) {
        denom += mm[e];
        acc = fmaf(mm[e], hv[e], acc);
      }
    }
    const float val = acc / denom;
    out_pre[((uint)node << 6) + lane] = f2bf(val);
    sacc += val;
    sacc2 = fmaf(val, val, sacc2);
  }

  // fused BN statistics: block-reduce per-channel partials
  __shared__ float l0[256], l1[256];
  l0[tid] = sacc;
  l1[tid] = sacc2;
  __syncthreads();
  if (tid < 64) {
    float a0 = l0[tid] + l0[tid + 64] + l0[tid + 128] + l0[tid + 192];
    float a1 = l1[tid] + l1[tid + 64] + l1[tid + 128] + l1[tid + 192];
    atomicAdd(&sums[tid], a0);
    atomicAdd(&sums[64 + tid], a1);
  }
}

// ---------------- Kernel 7: BN + ELU + residual (4 elems/thread) ----------------
__global__ __launch_bounds__(256) void final_kernel(
    const uint* __restrict__ out_pre_u, const uint* __restrict__ res_u,
    const float* __restrict__ sums, const float* __restrict__ gamma,
    const float* __restrict__ beta, float* __restrict__ out) {
  const int i = blockIdx.x * 256 + threadIdx.x;     // quad index; 3125*256 == NN*HC/4
  const int c4 = (i & 15) * 4;
  const float inv_n = 1.0f / (float)NN;
  uint2 op = *(const uint2*)&out_pre_u[(size_t)i * 2];
  uint2 rs = *(const uint2*)&res_u[(size_t)i * 2];
  float4 g4 = *(const float4*)&gamma[c4];
  float4 b4 = *(const float4*)&beta[c4];
  float pv[4] = { bf2f((ushort)(op.x & 0xFFFFu)), bf2f((ushort)(op.x >> 16)),
                  bf2f((ushort)(op.y & 0xFFFFu)), bf2f((ushort)(op.y >> 16)) };
  float rv[4] = { bf2f((ushort)(rs.x & 0xFFFFu)), bf2f((ushort)(rs.x >> 16)),
                  bf2f((ushort)(rs.y & 0xFFFFu)), bf2f((ushort)(rs.y >> 16)) };
  float gg[4] = { g4.x, g4.y, g4.z, g4.w };
  float bb[4] = { b4.x, b4.y, b4.z, b4.w };
  float4 o;
  float* po = &o.x;
#pragma unroll
  for (int k = 0; k < 4; ++k) {
    int c = c4 + k;
    float mu = sums[c] * inv_n;
    float var = sums[64 + c] * inv_n - mu * mu;
    float rinv = rsqrtf(var + BN_EPS);
    float v = (pv[k] - mu) * rinv * gg[k] + bb[k];
    v = v > 0.f ? v : (__expf(v) - 1.0f);
    po[k] = v + rv[k];
  }
  *(float4*)&out[(size_t)i * 4] = o;
}

extern "C" void kernel_launch(void* const* d_in, const int* in_sizes, int n_in,
                              void* d_out, int out_size, void* d_ws, size_t ws_size,
                              hipStream_t stream) {
  const float* x     = (const float*)d_in[0];
  const int*   ei    = (const int*)d_in[1];     // [2,E]: src = ei, dst = ei+E
  const float* W     = (const float*)d_in[2];
  const float* a_src = (const float*)d_in[3];
  const float* a_dst = (const float*)d_in[4];
  // d_in[5] = bias: cancels exactly through BatchNorm mean-subtraction -> unused
  const float* gamma = (const float*)d_in[6];
  const float* beta  = (const float*)d_in[7];
  const float* Wres  = (const float*)d_in[8];
  float* out = (float*)d_out;

  char* ws = (char*)d_ws;
  ushort* h        = (ushort*)ws; ws += (size_t)NN * HC * 2;   // bf16 h
  ushort* resb     = (ushort*)ws; ws += (size_t)NN * HC * 2;   // bf16 res
  ushort* out_pre  = (ushort*)ws; ws += (size_t)NN * HC * 2;   // bf16 out_pre
  float* al_s      = (float*)ws;  ws += (size_t)NN * 4 * 4;
  float* al_d      = (float*)ws;  ws += (size_t)NN * 4 * 4;
  float* sums      = (float*)ws;  ws += 128 * 4;               // [0:64]=sum, [64:128]=sumsq
  int*   row_ptr   = (int*)ws;    ws += (size_t)(NN + 1) * 4;
  int*   histmat   = (int*)ws;    ws += (size_t)TOTH * 4;      // [bucket][block]
  int*   histabs   = (int*)ws;    ws += (size_t)TOTH * 4;
  int*   bucket_base = (int*)ws;  ws += (NBKT + 1) * 4;
  uint*  pairs     = (uint*)ws;   ws += (size_t)EE * 4;
  int*   col       = (int*)ws;    ws += (size_t)EE * 4;

  gemm_mfma_kernel<<<(NN + 63) / 64, 256, 0, stream>>>(x, W, Wres, a_src, a_dst,
                                                       h, resb, al_s, al_d);
  histB_kernel<<<NBLKS, 256, 0, stream>>>(ei + EE, histmat, sums);
  scanB_kernel<<<NBKT, 256, 0, stream>>>(histmat, histabs, bucket_base);
  placeB_kernel<<<NBLKS, 256, 0, stream>>>(ei, ei + EE, histabs, pairs);
  bscatter_kernel<<<NBKT, 256, 0, stream>>>(pairs, bucket_base, row_ptr, col);
  node_kernel<<<NODE_GRID, 256, 0, stream>>>(h, al_s, al_d, row_ptr, col, out_pre, sums);
  final_kernel<<<NN * HC / 1024, 256, 0, stream>>>((const uint*)out_pre, (const uint*)resb,
                                                   sums, gamma, beta, out);
}

// Round 17
// 130.798 us; speedup vs baseline: 1.1269x; 1.1269x over previous
//
#include <hip/hip_runtime.h>
#include <hip/hip_bf16.h>

#define NN 50000
#define EE 800000
#define IN_F 128
#define HC 64
#define NEG_SLOPE 0.2f
#define BN_EPS 1e-5f

#define NBKT 196          // buckets of 256 nodes: dst>>8 (max 49999>>8 = 195)
#define NBLKS 250         // sort blocks (250 x 3200 = 800000; 1000 waves ~ full occupancy)
#define EPB2 (EE / NBLKS) // 3200 edges per sort block
#define TOTH (NBKT * NBLKS)  // 49000

typedef __attribute__((ext_vector_type(8))) short short8;
typedef __attribute__((ext_vector_type(4))) float f32x4;

__device__ __forceinline__ ushort f2bf(float f) {
  uint u = __float_as_uint(f);
  uint r = u + 0x7FFF + ((u >> 16) & 1);   // RNE
  return (ushort)(r >> 16);
}
__device__ __forceinline__ float bf2f(ushort u) {
  return __uint_as_float(((uint)u) << 16);
}

// ---------------- Kernel 1: MFMA bf16 GEMM: h=x@W (bf16), res=x@Wres (bf16), al_s, al_d --
__global__ __launch_bounds__(256) void gemm_mfma_kernel(
    const float* __restrict__ x, const float* __restrict__ W, const float* __restrict__ Wres,
    const float* __restrict__ a_src, const float* __restrict__ a_dst,
    ushort* __restrict__ h, ushort* __restrict__ res,
    float* __restrict__ al_s, float* __restrict__ al_d) {
  __shared__ ushort bs[128 * 128];   // [col][k] bf16, swizzled: byte ^= (col&7)<<4
  __shared__ ushort xs[64 * 128];    // [row][k] bf16, swizzled: byte ^= (row&7)<<4

  const int tid = threadIdx.x;
  const int r0 = blockIdx.x * 64;

  {
    const int c4 = (tid & 31) * 4;
    const int kb = (tid >> 5) * 16;
    const float* src0 = (c4 < HC) ? (W + c4) : (Wres + (c4 - HC));
    char* base = (char*)bs;
#pragma unroll
    for (int j = 0; j < 8; ++j) {
      int k0 = kb + j * 2;
      float4 fa = *(const float4*)(src0 + (size_t)k0 * HC);
      float4 fb = *(const float4*)(src0 + (size_t)(k0 + 1) * HC);
      uint p0 = (uint)f2bf(fa.x) | ((uint)f2bf(fb.x) << 16);
      uint p1 = (uint)f2bf(fa.y) | ((uint)f2bf(fb.y) << 16);
      uint p2 = (uint)f2bf(fa.z) | ((uint)f2bf(fb.z) << 16);
      uint p3 = (uint)f2bf(fa.w) | ((uint)f2bf(fb.w) << 16);
      *(uint*)(base + (((c4 + 0) * 256 + k0 * 2) ^ (((c4 + 0) & 7) << 4))) = p0;
      *(uint*)(base + (((c4 + 1) * 256 + k0 * 2) ^ (((c4 + 1) & 7) << 4))) = p1;
      *(uint*)(base + (((c4 + 2) * 256 + k0 * 2) ^ (((c4 + 2) & 7) << 4))) = p2;
      *(uint*)(base + (((c4 + 3) * 256 + k0 * 2) ^ (((c4 + 3) & 7) << 4))) = p3;
    }
  }
  {
    char* base = (char*)xs;
#pragma unroll
    for (int i = 0; i < 8; ++i) {
      int f4 = i * 256 + tid;
      int row = f4 >> 5;
      int kq = (f4 & 31) * 4;
      int gr = r0 + row;
      float4 v = make_float4(0.f, 0.f, 0.f, 0.f);
      if (gr < NN) v = *(const float4*)(x + (size_t)gr * IN_F + kq);
      uint lo = (uint)f2bf(v.x) | ((uint)f2bf(v.y) << 16);
      uint hi = (uint)f2bf(v.z) | ((uint)f2bf(v.w) << 16);
      uint off = (uint)((row * 256 + kq * 2) ^ ((row & 7) << 4));
      *(uint2*)(base + off) = make_uint2(lo, hi);
    }
  }
  __syncthreads();

  const int w = tid >> 6;
  const int l = tid & 63;
  const int lr = l & 15;
  const int lk = (l >> 4) * 8;

  f32x4 acc[8];
#pragma unroll
  for (int i = 0; i < 8; ++i) acc[i] = (f32x4){0.f, 0.f, 0.f, 0.f};

  const char* xb = (const char*)xs;
  const char* bb = (const char*)bs;
  const int arow = w * 16 + lr;
#pragma unroll
  for (int ks = 0; ks < 4; ++ks) {
    const int kbase = ks * 32 + lk;
    short8 af = *(const short8*)(xb + ((arow * 256 + kbase * 2) ^ ((arow & 7) << 4)));
#pragma unroll
    for (int ct = 0; ct < 8; ++ct) {
      const int c = ct * 16 + lr;
      short8 bfr = *(const short8*)(bb + ((c * 256 + kbase * 2) ^ ((c & 7) << 4)));
      acc[ct] = __builtin_amdgcn_mfma_f32_16x16x32_bf16(af, bfr, acc[ct], 0, 0, 0);
    }
  }

  const int rb = r0 + w * 16;
#pragma unroll
  for (int ct = 0; ct < 8; ++ct) {
#pragma unroll
    for (int r = 0; r < 4; ++r) {
      int gr = rb + (l >> 4) * 4 + r;
      if (gr < NN) {
        if (ct < 4) h[(size_t)gr * HC + ct * 16 + lr] = f2bf(acc[ct][r]);
        else        res[(size_t)gr * HC + (ct - 4) * 16 + lr] = f2bf(acc[ct][r]);
      }
    }
  }

  float myS[4] = {0.f, 0.f, 0.f, 0.f};
  float myD[4] = {0.f, 0.f, 0.f, 0.f};
#pragma unroll
  for (int ct = 0; ct < 4; ++ct) {
    float asv = a_src[ct * 16 + lr];
    float adv = a_dst[ct * 16 + lr];
#pragma unroll
    for (int r = 0; r < 4; ++r) {
      float ps = acc[ct][r] * asv;
      float pd = acc[ct][r] * adv;
      ps += __shfl_xor(ps, 1); ps += __shfl_xor(ps, 2); ps += __shfl_xor(ps, 4); ps += __shfl_xor(ps, 8);
      pd += __shfl_xor(pd, 1); pd += __shfl_xor(pd, 2); pd += __shfl_xor(pd, 4); pd += __shfl_xor(pd, 8);
      if (lr == ct) { myS[r] = ps; myD[r] = pd; }
    }
  }
  if (lr < 4) {
#pragma unroll
    for (int r = 0; r < 4; ++r) {
      int gr = rb + (l >> 4) * 4 + r;
      if (gr < NN) {
        al_s[gr * 4 + lr] = myS[r];
        al_d[gr * 4 + lr] = myD[r];
      }
    }
  }
}

// ---------------- Kernel 2: per-block bucket histogram, int4-vectorized ----------------
__global__ __launch_bounds__(256) void histB_kernel(const int* __restrict__ dst,
                                                    int* __restrict__ histmat,
                                                    float* __restrict__ sums) {
  __shared__ int lh[NBKT];
  const int tid = threadIdx.x;
  if (blockIdx.x == 0 && tid < 32)
    ((float4*)sums)[tid] = make_float4(0.f, 0.f, 0.f, 0.f);   // 128 floats
  for (int i = tid; i < NBKT; i += 256) lh[i] = 0;
  __syncthreads();
  const int4* d4 = (const int4*)(dst + blockIdx.x * EPB2);
  for (int p = tid; p < EPB2 / 4; p += 256) {
    int4 d = d4[p];
    atomicAdd(&lh[d.x >> 8], 1);
    atomicAdd(&lh[d.y >> 8], 1);
    atomicAdd(&lh[d.z >> 8], 1);
    atomicAdd(&lh[d.w >> 8], 1);
  }
  __syncthreads();
  for (int i = tid; i < NBKT; i += 256) histmat[i * NBLKS + blockIdx.x] = lh[i];
}

// ---------------- Kernel 3: per-bucket absolute bases (196 independent blocks) ---------
__global__ __launch_bounds__(256) void scanB_kernel(const int* __restrict__ histmat,
                                                    int* __restrict__ histabs,
                                                    int* __restrict__ bucket_base) {
  const int b = blockIdx.x;
  const int t = threadIdx.x;
  const int lane = t & 63;
  const int wv = t >> 6;
  int part = 0;
  for (int i = t; i < b * NBLKS; i += 256) part += histmat[i];
#pragma unroll
  for (int off = 1; off < 64; off <<= 1) part += __shfl_xor(part, off);
  __shared__ int ws1[4];
  if (lane == 0) ws1[wv] = part;
  __syncthreads();
  const int prefix = ws1[0] + ws1[1] + ws1[2] + ws1[3];
  int v = (t < NBLKS) ? histmat[b * NBLKS + t] : 0;
  int incl = v;
#pragma unroll
  for (int off = 1; off < 64; off <<= 1) {
    int tt = __shfl_up(incl, off);
    if (lane >= off) incl += tt;
  }
  __shared__ int ws2[4];
  if (lane == 63) ws2[wv] = incl;
  __syncthreads();
  int woff = 0;
  for (int w = 0; w < wv; ++w) woff += ws2[w];
  if (t < NBLKS) histabs[b * NBLKS + t] = prefix + woff + incl - v;
  if (t == 0) bucket_base[b] = prefix;
  if (b == NBKT - 1 && t == 0) bucket_base[NBKT] = EE;
}

// ---------------- Kernel 4: place edges into bucket-sorted pairs (int4 loads) ----------
__global__ __launch_bounds__(256) void placeB_kernel(const int* __restrict__ src,
                                                     const int* __restrict__ dst,
                                                     const int* __restrict__ histabs,
                                                     uint* __restrict__ pairs) {
  __shared__ int cur[NBKT];
  const int tid = threadIdx.x;
  for (int i = tid; i < NBKT; i += 256) cur[i] = histabs[i * NBLKS + blockIdx.x];
  __syncthreads();
  const int4* s4 = (const int4*)(src + blockIdx.x * EPB2);
  const int4* d4 = (const int4*)(dst + blockIdx.x * EPB2);
  for (int p = tid; p < EPB2 / 4; p += 256) {
    int4 d = d4[p];
    int4 s = s4[p];
    int q;
    q = atomicAdd(&cur[d.x >> 8], 1); pairs[q] = ((uint)(d.x & 255) << 16) | (uint)s.x;
    q = atomicAdd(&cur[d.y >> 8], 1); pairs[q] = ((uint)(d.y & 255) << 16) | (uint)s.y;
    q = atomicAdd(&cur[d.z >> 8], 1); pairs[q] = ((uint)(d.z & 255) << 16) | (uint)s.z;
    q = atomicAdd(&cur[d.w >> 8], 1); pairs[q] = ((uint)(d.w & 255) << 16) | (uint)s.w;
  }
}

// ---------------- Kernel 5: fine scatter; derives row_ptr locally ----------------
__global__ __launch_bounds__(256) void bscatter_kernel(const uint* __restrict__ pairs,
                                                       const int* __restrict__ bucket_base,
                                                       int* __restrict__ row_ptr,
                                                       int* __restrict__ col) {
  __shared__ int cnt[256];
  __shared__ int wsum[4];
  const int b = blockIdx.x;
  const int tid = threadIdx.x;
  cnt[tid] = 0;
  __syncthreads();
  const int lo = bucket_base[b];
  const int hi = bucket_base[b + 1];
  for (int i = lo + tid; i < hi; i += 256)
    atomicAdd(&cnt[(pairs[i] >> 16) & 255], 1);
  __syncthreads();
  const int lane = tid & 63;
  const int wv = tid >> 6;
  const int v = cnt[tid];
  int incl = v;
#pragma unroll
  for (int off = 1; off < 64; off <<= 1) {
    int t = __shfl_up(incl, off);
    if (lane >= off) incl += t;
  }
  if (lane == 63) wsum[wv] = incl;
  __syncthreads();
  int woff = 0;
  for (int w = 0; w < wv; ++w) woff += wsum[w];
  const int excl = lo + woff + incl - v;
  __syncthreads();
  cnt[tid] = excl;                     // reuse as cursor
  const int node = (b << 8) + tid;
  if (node < NN) row_ptr[node] = excl;
  if (b == NBKT - 1 && tid == 255) row_ptr[NN] = EE;
  __syncthreads();
  for (int i = lo + tid; i < hi; i += 256) {
    uint u = pairs[i];
    int d = (u >> 16) & 255;
    int p = atomicAdd(&cnt[d], 1);
    col[p] = (int)(u & 0xFFFFu);
  }
}

// ---------------- Kernel 6: per-node aggregate (coop exp + flat batched gathers) -------
// EXACT R14 structure: one wave per node, 12500 blocks, no outer loop, no fused stats
// (R16 showed grid-stride + fused stats pushes ss/hv/mm[16] out of registers: VGPR 40,
// VALUBusy 20%, 3x slower).
__global__ __launch_bounds__(256) void node_kernel(
    const ushort* __restrict__ h, const float* __restrict__ al_s, const float* __restrict__ al_d,
    const int* __restrict__ row_ptr, const int* __restrict__ col,
    ushort* __restrict__ out_pre) {
  const int node = blockIdx.x * 4 + (threadIdx.x >> 6);
  const int lane = threadIdx.x & 63;
  const int head = lane >> 4;       // phase-B head (channel group)
  const int hdA = lane & 3;         // phase-A head
  const int elA = lane >> 2;        // phase-A edge slot (0..15)

  const float aldB = al_d[(uint)node * 4u + head];
  const float aldA = al_d[(uint)node * 4u + hdA];

  float e0 = al_s[(uint)node * 4u + head] + aldB;   // self loop
  e0 = e0 > 0.f ? e0 : NEG_SLOPE * e0;
  float m = __expf(e0);
  float denom = m;
  float acc = m * bf2f(h[((uint)node << 6) + lane]);

  const int beg = row_ptr[node];
  const int end = row_ptr[node + 1];
  for (int idx = beg; idx < end; idx += 16) {
    // phase A: one (edge, head) numerator per lane; 0 for tail slots
    const int j = idx + elA;
    const uint sA = (uint)col[j < end ? j : beg];
    float ee = al_s[sA * 4u + hdA] + aldA;
    ee = ee > 0.f ? ee : NEG_SLOPE * ee;
    const float mmA = (j < end) ? __expf(ee) : 0.f;
    // phase B: flat, branch-free
    uint ss[16];
#pragma unroll
    for (int e = 0; e < 16; ++e) ss[e] = (uint)__shfl((int)sA, e * 4);
    float hv[16];
#pragma unroll
    for (int e = 0; e < 16; ++e) hv[e] = bf2f(h[(ss[e] << 6) + lane]);
    float mm[16];
#pragma unroll
    for (int e = 0; e < 16; ++e) mm[e] = __shfl(mmA, e * 4 + head);
#pragma unroll
    for (int e = 0; e < 16; ++e) {
      denom += mm[e];
      acc = fmaf(mm[e], hv[e], acc);
    }
  }
  out_pre[((uint)node << 6) + lane] = f2bf(acc / denom);
}

// ---------------- Kernel 7: BN statistics (bf16 in, uint-paired loads) ----------------
__global__ __launch_bounds__(256) void stats_kernel(const uint* __restrict__ out_pre_u,
                                                    float* __restrict__ sums) {
  const int tid = threadIdx.x;
  const int c2 = tid & 31;             // channel pair: channels 2*c2, 2*c2+1
  const int rg = tid >> 5;             // 8 row groups
  float s0 = 0.f, s1 = 0.f, q0 = 0.f, q1 = 0.f;
  for (int r = blockIdx.x * 8 + rg; r < NN; r += gridDim.x * 8) {
    uint u = out_pre_u[((uint)r << 5) + c2];
    float v0 = bf2f((ushort)(u & 0xFFFFu));
    float v1 = bf2f((ushort)(u >> 16));
    s0 += v0; s1 += v1;
    q0 = fmaf(v0, v0, q0); q1 = fmaf(v1, v1, q1);
  }
  __shared__ float l0[256], l1[256], l2[256], l3[256];
  l0[tid] = s0; l1[tid] = s1; l2[tid] = q0; l3[tid] = q1;
  __syncthreads();
  if (tid < 32) {
    float a0 = 0.f, a1 = 0.f, a2 = 0.f, a3 = 0.f;
#pragma unroll
    for (int g = 0; g < 8; ++g) {
      a0 += l0[g * 32 + tid]; a1 += l1[g * 32 + tid];
      a2 += l2[g * 32 + tid]; a3 += l3[g * 32 + tid];
    }
    atomicAdd(&sums[tid * 2], a0);
    atomicAdd(&sums[tid * 2 + 1], a1);
    atomicAdd(&sums[64 + tid * 2], a2);
    atomicAdd(&sums[64 + tid * 2 + 1], a3);
  }
}

// ---------------- Kernel 8: BN + ELU + residual (4 elems/thread) ----------------
__global__ __launch_bounds__(256) void final_kernel(
    const uint* __restrict__ out_pre_u, const uint* __restrict__ res_u,
    const float* __restrict__ sums, const float* __restrict__ gamma,
    const float* __restrict__ beta, float* __restrict__ out) {
  const int i = blockIdx.x * 256 + threadIdx.x;     // quad index; 3125*256 == NN*HC/4
  const int c4 = (i & 15) * 4;
  const float inv_n = 1.0f / (float)NN;
  uint2 op = *(const uint2*)&out_pre_u[(size_t)i * 2];
  uint2 rs = *(const uint2*)&res_u[(size_t)i * 2];
  float4 g4 = *(const float4*)&gamma[c4];
  float4 b4 = *(const float4*)&beta[c4];
  float pv[4] = { bf2f((ushort)(op.x & 0xFFFFu)), bf2f((ushort)(op.x >> 16)),
                  bf2f((ushort)(op.y & 0xFFFFu)), bf2f((ushort)(op.y >> 16)) };
  float rv[4] = { bf2f((ushort)(rs.x & 0xFFFFu)), bf2f((ushort)(rs.x >> 16)),
                  bf2f((ushort)(rs.y & 0xFFFFu)), bf2f((ushort)(rs.y >> 16)) };
  float gg[4] = { g4.x, g4.y, g4.z, g4.w };
  float bb[4] = { b4.x, b4.y, b4.z, b4.w };
  float4 o;
  float* po = &o.x;
#pragma unroll
  for (int k = 0; k < 4; ++k) {
    int c = c4 + k;
    float mu = sums[c] * inv_n;
    float var = sums[64 + c] * inv_n - mu * mu;
    float rinv = rsqrtf(var + BN_EPS);
    float v = (pv[k] - mu) * rinv * gg[k] + bb[k];
    v = v > 0.f ? v : (__expf(v) - 1.0f);
    po[k] = v + rv[k];
  }
  *(float4*)&out[(size_t)i * 4] = o;
}

extern "C" void kernel_launch(void* const* d_in, const int* in_sizes, int n_in,
                              void* d_out, int out_size, void* d_ws, size_t ws_size,
                              hipStream_t stream) {
  const float* x     = (const float*)d_in[0];
  const int*   ei    = (const int*)d_in[1];     // [2,E]: src = ei, dst = ei+E
  const float* W     = (const float*)d_in[2];
  const float* a_src = (const float*)d_in[3];
  const float* a_dst = (const float*)d_in[4];
  // d_in[5] = bias: cancels exactly through BatchNorm mean-subtraction -> unused
  const float* gamma = (const float*)d_in[6];
  const float* beta  = (const float*)d_in[7];
  const float* Wres  = (const float*)d_in[8];
  float* out = (float*)d_out;

  char* ws = (char*)d_ws;
  ushort* h        = (ushort*)ws; ws += (size_t)NN * HC * 2;   // bf16 h
  ushort* resb     = (ushort*)ws; ws += (size_t)NN * HC * 2;   // bf16 res
  ushort* out_pre  = (ushort*)ws; ws += (size_t)NN * HC * 2;   // bf16 out_pre
  float* al_s      = (float*)ws;  ws += (size_t)NN * 4 * 4;
  float* al_d      = (float*)ws;  ws += (size_t)NN * 4 * 4;
  float* sums      = (float*)ws;  ws += 128 * 4;               // [0:64]=sum, [64:128]=sumsq
  int*   row_ptr   = (int*)ws;    ws += (size_t)(NN + 1) * 4;
  int*   histmat   = (int*)ws;    ws += (size_t)TOTH * 4;      // [bucket][block]
  int*   histabs   = (int*)ws;    ws += (size_t)TOTH * 4;
  int*   bucket_base = (int*)ws;  ws += (NBKT + 1) * 4;
  uint*  pairs     = (uint*)ws;   ws += (size_t)EE * 4;
  int*   col       = (int*)ws;    ws += (size_t)EE * 4;

  gemm_mfma_kernel<<<(NN + 63) / 64, 256, 0, stream>>>(x, W, Wres, a_src, a_dst,
                                                       h, resb, al_s, al_d);
  histB_kernel<<<NBLKS, 256, 0, stream>>>(ei + EE, histmat, sums);
  scanB_kernel<<<NBKT, 256, 0, stream>>>(histmat, histabs, bucket_base);
  placeB_kernel<<<NBLKS, 256, 0, stream>>>(ei, ei + EE, histabs, pairs);
  bscatter_kernel<<<NBKT, 256, 0, stream>>>(pairs, bucket_base, row_ptr, col);
  node_kernel<<<NN / 4, 256, 0, stream>>>(h, al_s, al_d, row_ptr, col, out_pre);
  stats_kernel<<<256, 256, 0, stream>>>((const uint*)out_pre, sums);
  final_kernel<<<NN * HC / 1024, 256, 0, stream>>>((const uint*)out_pre, (const uint*)resb,
                                                   sums, gamma, beta, out);
}

// Round 18
// 122.646 us; speedup vs baseline: 1.2018x; 1.0665x over previous
//
#include <hip/hip_runtime.h>
#include <hip/hip_bf16.h>

#define NN 50000
#define EE 800000
#define IN_F 128
#define HC 64
#define NEG_SLOPE 0.2f
#define BN_EPS 1e-5f

#define NBKT 196          // buckets of 256 nodes: dst>>8 (max 49999>>8 = 195)
#define NBLKS 200         // sort blocks (200 x 4000 = 800000)
#define EPB2 (EE / NBLKS) // 4000 edges per sort block
#define TOTH (NBKT * NBLKS)  // 39200
#define GEMM_BLOCKS 512   // persistent gemm: B staged once/block, 2 blocks/CU
#define NTILES ((NN + 63) / 64)  // 782 row tiles

typedef __attribute__((ext_vector_type(8))) short short8;
typedef __attribute__((ext_vector_type(4))) float f32x4;

__device__ __forceinline__ ushort f2bf(float f) {
  uint u = __float_as_uint(f);
  uint r = u + 0x7FFF + ((u >> 16) & 1);   // RNE
  return (ushort)(r >> 16);
}
__device__ __forceinline__ float bf2f(ushort u) {
  return __uint_as_float(((uint)u) << 16);
}

// ---------------- Kernel 1: persistent MFMA bf16 GEMM ----------------
// B=[W|Wres] (64KB bf16, swizzled) staged ONCE per block; loop over row tiles
// (782 tiles / 512 blocks) re-staging only the 16KB x-tile. Saves 35% of the
// B-staging L2 traffic + f2bf VALU vs one-tile-per-block.
__global__ __launch_bounds__(256) void gemm_mfma_kernel(
    const float* __restrict__ x, const float* __restrict__ W, const float* __restrict__ Wres,
    const float* __restrict__ a_src, const float* __restrict__ a_dst,
    ushort* __restrict__ h, ushort* __restrict__ res,
    float* __restrict__ al_s, float* __restrict__ al_d) {
  __shared__ ushort bs[128 * 128];   // [col][k] bf16, swizzled: byte ^= (col&7)<<4
  __shared__ ushort xs[64 * 128];    // [row][k] bf16, swizzled: byte ^= (row&7)<<4

  const int tid = threadIdx.x;

  // ---- stage B once ----
  {
    const int c4 = (tid & 31) * 4;
    const int kb = (tid >> 5) * 16;
    const float* src0 = (c4 < HC) ? (W + c4) : (Wres + (c4 - HC));
    char* base = (char*)bs;
#pragma unroll
    for (int j = 0; j < 8; ++j) {
      int k0 = kb + j * 2;
      float4 fa = *(const float4*)(src0 + (size_t)k0 * HC);
      float4 fb = *(const float4*)(src0 + (size_t)(k0 + 1) * HC);
      uint p0 = (uint)f2bf(fa.x) | ((uint)f2bf(fb.x) << 16);
      uint p1 = (uint)f2bf(fa.y) | ((uint)f2bf(fb.y) << 16);
      uint p2 = (uint)f2bf(fa.z) | ((uint)f2bf(fb.z) << 16);
      uint p3 = (uint)f2bf(fa.w) | ((uint)f2bf(fb.w) << 16);
      *(uint*)(base + (((c4 + 0) * 256 + k0 * 2) ^ (((c4 + 0) & 7) << 4))) = p0;
      *(uint*)(base + (((c4 + 1) * 256 + k0 * 2) ^ (((c4 + 1) & 7) << 4))) = p1;
      *(uint*)(base + (((c4 + 2) * 256 + k0 * 2) ^ (((c4 + 2) & 7) << 4))) = p2;
      *(uint*)(base + (((c4 + 3) * 256 + k0 * 2) ^ (((c4 + 3) & 7) << 4))) = p3;
    }
  }

  const int w = tid >> 6;
  const int l = tid & 63;
  const int lr = l & 15;
  const int lk = (l >> 4) * 8;
  const char* xb = (const char*)xs;
  const char* bb = (const char*)bs;
  const int arow = w * 16 + lr;

  for (int rt = blockIdx.x; rt < NTILES; rt += GEMM_BLOCKS) {
    const int r0 = rt * 64;
    __syncthreads();   // B ready (1st iter) / previous iteration's xs reads complete
    {
      char* base = (char*)xs;
#pragma unroll
      for (int i = 0; i < 8; ++i) {
        int f4 = i * 256 + tid;
        int row = f4 >> 5;
        int kq = (f4 & 31) * 4;
        int gr = r0 + row;
        float4 v = make_float4(0.f, 0.f, 0.f, 0.f);
        if (gr < NN) v = *(const float4*)(x + (size_t)gr * IN_F + kq);
        uint lo = (uint)f2bf(v.x) | ((uint)f2bf(v.y) << 16);
        uint hi = (uint)f2bf(v.z) | ((uint)f2bf(v.w) << 16);
        uint off = (uint)((row * 256 + kq * 2) ^ ((row & 7) << 4));
        *(uint2*)(base + off) = make_uint2(lo, hi);
      }
    }
    __syncthreads();

    f32x4 acc[8];
#pragma unroll
    for (int i = 0; i < 8; ++i) acc[i] = (f32x4){0.f, 0.f, 0.f, 0.f};

#pragma unroll
    for (int ks = 0; ks < 4; ++ks) {
      const int kbase = ks * 32 + lk;
      short8 af = *(const short8*)(xb + ((arow * 256 + kbase * 2) ^ ((arow & 7) << 4)));
#pragma unroll
      for (int ct = 0; ct < 8; ++ct) {
        const int c = ct * 16 + lr;
        short8 bfr = *(const short8*)(bb + ((c * 256 + kbase * 2) ^ ((c & 7) << 4)));
        acc[ct] = __builtin_amdgcn_mfma_f32_16x16x32_bf16(af, bfr, acc[ct], 0, 0, 0);
      }
    }

    const int rb = r0 + w * 16;
#pragma unroll
    for (int ct = 0; ct < 8; ++ct) {
#pragma unroll
      for (int r = 0; r < 4; ++r) {
        int gr = rb + (l >> 4) * 4 + r;
        if (gr < NN) {
          if (ct < 4) h[(size_t)gr * HC + ct * 16 + lr] = f2bf(acc[ct][r]);
          else        res[(size_t)gr * HC + (ct - 4) * 16 + lr] = f2bf(acc[ct][r]);
        }
      }
    }

    float myS[4] = {0.f, 0.f, 0.f, 0.f};
    float myD[4] = {0.f, 0.f, 0.f, 0.f};
#pragma unroll
    for (int ct = 0; ct < 4; ++ct) {
      float asv = a_src[ct * 16 + lr];
      float adv = a_dst[ct * 16 + lr];
#pragma unroll
      for (int r = 0; r < 4; ++r) {
        float ps = acc[ct][r] * asv;
        float pd = acc[ct][r] * adv;
        ps += __shfl_xor(ps, 1); ps += __shfl_xor(ps, 2); ps += __shfl_xor(ps, 4); ps += __shfl_xor(ps, 8);
        pd += __shfl_xor(pd, 1); pd += __shfl_xor(pd, 2); pd += __shfl_xor(pd, 4); pd += __shfl_xor(pd, 8);
        if (lr == ct) { myS[r] = ps; myD[r] = pd; }
      }
    }
    if (lr < 4) {
#pragma unroll
      for (int r = 0; r < 4; ++r) {
        int gr = rb + (l >> 4) * 4 + r;
        if (gr < NN) {
          al_s[gr * 4 + lr] = myS[r];
          al_d[gr * 4 + lr] = myD[r];
        }
      }
    }
  }
}

// ---------------- Kernel 2: per-block bucket histogram, int4-vectorized ----------------
__global__ __launch_bounds__(256) void histB_kernel(const int* __restrict__ dst,
                                                    int* __restrict__ histmat,
                                                    float* __restrict__ sums) {
  __shared__ int lh[NBKT];
  const int tid = threadIdx.x;
  if (blockIdx.x == 0 && tid < 32)
    ((float4*)sums)[tid] = make_float4(0.f, 0.f, 0.f, 0.f);   // 128 floats
  for (int i = tid; i < NBKT; i += 256) lh[i] = 0;
  __syncthreads();
  const int4* d4 = (const int4*)(dst + blockIdx.x * EPB2);
  for (int p = tid; p < EPB2 / 4; p += 256) {
    int4 d = d4[p];
    atomicAdd(&lh[d.x >> 8], 1);
    atomicAdd(&lh[d.y >> 8], 1);
    atomicAdd(&lh[d.z >> 8], 1);
    atomicAdd(&lh[d.w >> 8], 1);
  }
  __syncthreads();
  for (int i = tid; i < NBKT; i += 256) histmat[i * NBLKS + blockIdx.x] = lh[i];
}

// ---------------- Kernel 3: per-bucket absolute bases (196 independent blocks) ---------
__global__ __launch_bounds__(256) void scanB_kernel(const int* __restrict__ histmat,
                                                    int* __restrict__ histabs,
                                                    int* __restrict__ bucket_base) {
  const int b = blockIdx.x;
  const int t = threadIdx.x;
  const int lane = t & 63;
  const int wv = t >> 6;
  int part = 0;
  for (int i = t; i < b * NBLKS; i += 256) part += histmat[i];
#pragma unroll
  for (int off = 1; off < 64; off <<= 1) part += __shfl_xor(part, off);
  __shared__ int ws1[4];
  if (lane == 0) ws1[wv] = part;
  __syncthreads();
  const int prefix = ws1[0] + ws1[1] + ws1[2] + ws1[3];
  int v = (t < NBLKS) ? histmat[b * NBLKS + t] : 0;
  int incl = v;
#pragma unroll
  for (int off = 1; off < 64; off <<= 1) {
    int tt = __shfl_up(incl, off);
    if (lane >= off) incl += tt;
  }
  __shared__ int ws2[4];
  if (lane == 63) ws2[wv] = incl;
  __syncthreads();
  int woff = 0;
  for (int w = 0; w < wv; ++w) woff += ws2[w];
  if (t < NBLKS) histabs[b * NBLKS + t] = prefix + woff + incl - v;
  if (t == 0) bucket_base[b] = prefix;
  if (b == NBKT - 1 && t == 0) bucket_base[NBKT] = EE;
}

// ---------------- Kernel 4: place edges into bucket-sorted pairs (int4 loads) ----------
__global__ __launch_bounds__(256) void placeB_kernel(const int* __restrict__ src,
                                                     const int* __restrict__ dst,
                                                     const int* __restrict__ histabs,
                                                     uint* __restrict__ pairs) {
  __shared__ int cur[NBKT];
  const int tid = threadIdx.x;
  for (int i = tid; i < NBKT; i += 256) cur[i] = histabs[i * NBLKS + blockIdx.x];
  __syncthreads();
  const int4* s4 = (const int4*)(src + blockIdx.x * EPB2);
  const int4* d4 = (const int4*)(dst + blockIdx.x * EPB2);
  for (int p = tid; p < EPB2 / 4; p += 256) {
    int4 d = d4[p];
    int4 s = s4[p];
    int q;
    q = atomicAdd(&cur[d.x >> 8], 1); pairs[q] = ((uint)(d.x & 255) << 16) | (uint)s.x;
    q = atomicAdd(&cur[d.y >> 8], 1); pairs[q] = ((uint)(d.y & 255) << 16) | (uint)s.y;
    q = atomicAdd(&cur[d.z >> 8], 1); pairs[q] = ((uint)(d.z & 255) << 16) | (uint)s.z;
    q = atomicAdd(&cur[d.w >> 8], 1); pairs[q] = ((uint)(d.w & 255) << 16) | (uint)s.w;
  }
}

// ---------------- Kernel 5: fine scatter; derives row_ptr locally ----------------
__global__ __launch_bounds__(256) void bscatter_kernel(const uint* __restrict__ pairs,
                                                       const int* __restrict__ bucket_base,
                                                       int* __restrict__ row_ptr,
                                                       int* __restrict__ col) {
  __shared__ int cnt[256];
  __shared__ int wsum[4];
  const int b = blockIdx.x;
  const int tid = threadIdx.x;
  cnt[tid] = 0;
  __syncthreads();
  const int lo = bucket_base[b];
  const int hi = bucket_base[b + 1];
  for (int i = lo + tid; i < hi; i += 256)
    atomicAdd(&cnt[(pairs[i] >> 16) & 255], 1);
  __syncthreads();
  const int lane = tid & 63;
  const int wv = tid >> 6;
  const int v = cnt[tid];
  int incl = v;
#pragma unroll
  for (int off = 1; off < 64; off <<= 1) {
    int t = __shfl_up(incl, off);
    if (lane >= off) incl += t;
  }
  if (lane == 63) wsum[wv] = incl;
  __syncthreads();
  int woff = 0;
  for (int w = 0; w < wv; ++w) woff += wsum[w];
  const int excl = lo + woff + incl - v;
  __syncthreads();
  cnt[tid] = excl;                     // reuse as cursor
  const int node = (b << 8) + tid;
  if (node < NN) row_ptr[node] = excl;
  if (b == NBKT - 1 && tid == 255) row_ptr[NN] = EE;
  __syncthreads();
  for (int i = lo + tid; i < hi; i += 256) {
    uint u = pairs[i];
    int d = (u >> 16) & 255;
    int p = atomicAdd(&cnt[d], 1);
    col[p] = (int)(u & 0xFFFFu);
  }
}

// ---------------- Kernel 6: per-node aggregate (coop exp + flat batched gathers) -------
// EXACT R14 structure: one wave per node, 12500 blocks (R16 showed grid-stride + fused
// stats pushes ss/hv/mm[16] out of registers and serializes the gathers).
__global__ __launch_bounds__(256) void node_kernel(
    const ushort* __restrict__ h, const float* __restrict__ al_s, const float* __restrict__ al_d,
    const int* __restrict__ row_ptr, const int* __restrict__ col,
    ushort* __restrict__ out_pre) {
  const int node = blockIdx.x * 4 + (threadIdx.x >> 6);
  const int lane = threadIdx.x & 63;
  const int head = lane >> 4;       // phase-B head (channel group)
  const int hdA = lane & 3;         // phase-A head
  const int elA = lane >> 2;        // phase-A edge slot (0..15)

  const float aldB = al_d[(uint)node * 4u + head];
  const float aldA = al_d[(uint)node * 4u + hdA];

  float e0 = al_s[(uint)node * 4u + head] + aldB;   // self loop
  e0 = e0 > 0.f ? e0 : NEG_SLOPE * e0;
  float m = __expf(e0);
  float denom = m;
  float acc = m * bf2f(h[((uint)node << 6) + lane]);

  const int beg = row_ptr[node];
  const int end = row_ptr[node + 1];
  for (int idx = beg; idx < end; idx += 16) {
    // phase A: one (edge, head) numerator per lane; 0 for tail slots
    const int j = idx + elA;
    const uint sA = (uint)col[j < end ? j : beg];
    float ee = al_s[sA * 4u + hdA] + aldA;
    ee = ee > 0.f ? ee : NEG_SLOPE * ee;
    const float mmA = (j < end) ? __expf(ee) : 0.f;
    // phase B: flat, branch-free
    uint ss[16];
#pragma unroll
    for (int e = 0; e < 16; ++e) ss[e] = (uint)__shfl((int)sA, e * 4);
    float hv[16];
#pragma unroll
    for (int e = 0; e < 16; ++e) hv[e] = bf2f(h[(ss[e] << 6) + lane]);
    float mm[16];
#pragma unroll
    for (int e = 0; e < 16; ++e) mm[e] = __shfl(mmA, e * 4 + head);
#pragma unroll
    for (int e = 0; e < 16; ++e) {
      denom += mm[e];
      acc = fmaf(mm[e], hv[e], acc);
    }
  }
  out_pre[((uint)node << 6) + lane] = f2bf(acc / denom);
}

// ---------------- Kernel 7: BN statistics (bf16 in, uint-paired loads) ----------------
__global__ __launch_bounds__(256) void stats_kernel(const uint* __restrict__ out_pre_u,
                                                    float* __restrict__ sums) {
  const int tid = threadIdx.x;
  const int c2 = tid & 31;             // channel pair: channels 2*c2, 2*c2+1
  const int rg = tid >> 5;             // 8 row groups
  float s0 = 0.f, s1 = 0.f, q0 = 0.f, q1 = 0.f;
  for (int r = blockIdx.x * 8 + rg; r < NN; r += gridDim.x * 8) {
    uint u = out_pre_u[((uint)r << 5) + c2];
    float v0 = bf2f((ushort)(u & 0xFFFFu));
    float v1 = bf2f((ushort)(u >> 16));
    s0 += v0; s1 += v1;
    q0 = fmaf(v0, v0, q0); q1 = fmaf(v1, v1, q1);
  }
  __shared__ float l0[256], l1[256], l2[256], l3[256];
  l0[tid] = s0; l1[tid] = s1; l2[tid] = q0; l3[tid] = q1;
  __syncthreads();
  if (tid < 32) {
    float a0 = 0.f, a1 = 0.f, a2 = 0.f, a3 = 0.f;
#pragma unroll
    for (int g = 0; g < 8; ++g) {
      a0 += l0[g * 32 + tid]; a1 += l1[g * 32 + tid];
      a2 += l2[g * 32 + tid]; a3 += l3[g * 32 + tid];
    }
    atomicAdd(&sums[tid * 2], a0);
    atomicAdd(&sums[tid * 2 + 1], a1);
    atomicAdd(&sums[64 + tid * 2], a2);
    atomicAdd(&sums[64 + tid * 2 + 1], a3);
  }
}

// ---------------- Kernel 8: BN + ELU + residual (4 elems/thread) ----------------
__global__ __launch_bounds__(256) void final_kernel(
    const uint* __restrict__ out_pre_u, const uint* __restrict__ res_u,
    const float* __restrict__ sums, const float* __restrict__ gamma,
    const float* __restrict__ beta, float* __restrict__ out) {
  const int i = blockIdx.x * 256 + threadIdx.x;     // quad index; 3125*256 == NN*HC/4
  const int c4 = (i & 15) * 4;
  const float inv_n = 1.0f / (float)NN;
  uint2 op = *(const uint2*)&out_pre_u[(size_t)i * 2];
  uint2 rs = *(const uint2*)&res_u[(size_t)i * 2];
  float4 g4 = *(const float4*)&gamma[c4];
  float4 b4 = *(const float4*)&beta[c4];
  float pv[4] = { bf2f((ushort)(op.x & 0xFFFFu)), bf2f((ushort)(op.x >> 16)),
                  bf2f((ushort)(op.y & 0xFFFFu)), bf2f((ushort)(op.y >> 16)) };
  float rv[4] = { bf2f((ushort)(rs.x & 0xFFFFu)), bf2f((ushort)(rs.x >> 16)),
                  bf2f((ushort)(rs.y & 0xFFFFu)), bf2f((ushort)(rs.y >> 16)) };
  float gg[4] = { g4.x, g4.y, g4.z, g4.w };
  float bb[4] = { b4.x, b4.y, b4.z, b4.w };
  float4 o;
  float* po = &o.x;
#pragma unroll
  for (int k = 0; k < 4; ++k) {
    int c = c4 + k;
    float mu = sums[c] * inv_n;
    float var = sums[64 + c] * inv_n - mu * mu;
    float rinv = rsqrtf(var + BN_EPS);
    float v = (pv[k] - mu) * rinv * gg[k] + bb[k];
    v = v > 0.f ? v : (__expf(v) - 1.0f);
    po[k] = v + rv[k];
  }
  *(float4*)&out[(size_t)i * 4] = o;
}

extern "C" void kernel_launch(void* const* d_in, const int* in_sizes, int n_in,
                              void* d_out, int out_size, void* d_ws, size_t ws_size,
                              hipStream_t stream) {
  const float* x     = (const float*)d_in[0];
  const int*   ei    = (const int*)d_in[1];     // [2,E]: src = ei, dst = ei+E
  const float* W     = (const float*)d_in[2];
  const float* a_src = (const float*)d_in[3];
  const float* a_dst = (const float*)d_in[4];
  // d_in[5] = bias: cancels exactly through BatchNorm mean-subtraction -> unused
  const float* gamma = (const float*)d_in[6];
  const float* beta  = (const float*)d_in[7];
  const float* Wres  = (const float*)d_in[8];
  float* out = (float*)d_out;

  char* ws = (char*)d_ws;
  ushort* h        = (ushort*)ws; ws += (size_t)NN * HC * 2;   // bf16 h
  ushort* resb     = (ushort*)ws; ws += (size_t)NN * HC * 2;   // bf16 res
  ushort* out_pre  = (ushort*)ws; ws += (size_t)NN * HC * 2;   // bf16 out_pre
  float* al_s      = (float*)ws;  ws += (size_t)NN * 4 * 4;
  float* al_d      = (float*)ws;  ws += (size_t)NN * 4 * 4;
  float* sums      = (float*)ws;  ws += 128 * 4;               // [0:64]=sum, [64:128]=sumsq
  int*   row_ptr   = (int*)ws;    ws += (size_t)(NN + 1) * 4;
  int*   histmat   = (int*)ws;    ws += (size_t)TOTH * 4;      // [bucket][block]
  int*   histabs   = (int*)ws;    ws += (size_t)TOTH * 4;
  int*   bucket_base = (int*)ws;  ws += (NBKT + 1) * 4;
  uint*  pairs     = (uint*)ws;   ws += (size_t)EE * 4;
  int*   col       = (int*)ws;    ws += (size_t)EE * 4;

  gemm_mfma_kernel<<<GEMM_BLOCKS, 256, 0, stream>>>(x, W, Wres, a_src, a_dst,
                                                    h, resb, al_s, al_d);
  histB_kernel<<<NBLKS, 256, 0, stream>>>(ei + EE, histmat, sums);
  scanB_kernel<<<NBKT, 256, 0, stream>>>(histmat, histabs, bucket_base);
  placeB_kernel<<<NBLKS, 256, 0, stream>>>(ei, ei + EE, histabs, pairs);
  bscatter_kernel<<<NBKT, 256, 0, stream>>>(pairs, bucket_base, row_ptr, col);
  node_kernel<<<NN / 4, 256, 0, stream>>>(h, al_s, al_d, row_ptr, col, out_pre);
  stats_kernel<<<256, 256, 0, stream>>>((const uint*)out_pre, sums);
  final_kernel<<<NN * HC / 1024, 256, 0, stream>>>((const uint*)out_pre, (const uint*)resb,
                                                   sums, gamma, beta, out);
}

// Round 19
// 105.216 us; speedup vs baseline: 1.4009x; 1.1657x over previous
//
#include <hip/hip_runtime.h>
#include <hip/hip_bf16.h>

#define NN 50000
#define EE 800000
#define IN_F 128
#define HC 64
#define NEG_SLOPE 0.2f
#define BN_EPS 1e-5f

#define NBKT 196          // buckets of 256 nodes: dst>>8 (max 49999>>8 = 195)
#define NBLKS 200         // sort blocks (200 x 4000 = 800000)
#define EPB2 (EE / NBLKS) // 4000 edges per sort block
#define TOTH (NBKT * NBLKS)  // 39200
#define GEMM_BLOCKS 391   // persistent gemm: exactly 2 tiles/block (391*2 = 782)
#define NTILES ((NN + 63) / 64)  // 782 row tiles

typedef __attribute__((ext_vector_type(8))) short short8;
typedef __attribute__((ext_vector_type(4))) float f32x4;

__device__ __forceinline__ ushort f2bf(float f) {
  uint u = __float_as_uint(f);
  uint r = u + 0x7FFF + ((u >> 16) & 1);   // RNE
  return (ushort)(r >> 16);
}
__device__ __forceinline__ float bf2f(ushort u) {
  return __uint_as_float(((uint)u) << 16);
}

// ---------------- Kernel 1: persistent MFMA bf16 GEMM ----------------
// B=[W|Wres] (64KB bf16, swizzled) staged ONCE per block; exactly 2 row tiles/block.
__global__ __launch_bounds__(256) void gemm_mfma_kernel(
    const float* __restrict__ x, const float* __restrict__ W, const float* __restrict__ Wres,
    const float* __restrict__ a_src, const float* __restrict__ a_dst,
    ushort* __restrict__ h, ushort* __restrict__ res,
    float* __restrict__ al_s, float* __restrict__ al_d) {
  __shared__ ushort bs[128 * 128];   // [col][k] bf16, swizzled: byte ^= (col&7)<<4
  __shared__ ushort xs[64 * 128];    // [row][k] bf16, swizzled: byte ^= (row&7)<<4

  const int tid = threadIdx.x;

  // ---- stage B once ----
  {
    const int c4 = (tid & 31) * 4;
    const int kb = (tid >> 5) * 16;
    const float* src0 = (c4 < HC) ? (W + c4) : (Wres + (c4 - HC));
    char* base = (char*)bs;
#pragma unroll
    for (int j = 0; j < 8; ++j) {
      int k0 = kb + j * 2;
      float4 fa = *(const float4*)(src0 + (size_t)k0 * HC);
      float4 fb = *(const float4*)(src0 + (size_t)(k0 + 1) * HC);
      uint p0 = (uint)f2bf(fa.x) | ((uint)f2bf(fb.x) << 16);
      uint p1 = (uint)f2bf(fa.y) | ((uint)f2bf(fb.y) << 16);
      uint p2 = (uint)f2bf(fa.z) | ((uint)f2bf(fb.z) << 16);
      uint p3 = (uint)f2bf(fa.w) | ((uint)f2bf(fb.w) << 16);
      *(uint*)(base + (((c4 + 0) * 256 + k0 * 2) ^ (((c4 + 0) & 7) << 4))) = p0;
      *(uint*)(base + (((c4 + 1) * 256 + k0 * 2) ^ (((c4 + 1) & 7) << 4))) = p1;
      *(uint*)(base + (((c4 + 2) * 256 + k0 * 2) ^ (((c4 + 2) & 7) << 4))) = p2;
      *(uint*)(base + (((c4 + 3) * 256 + k0 * 2) ^ (((c4 + 3) & 7) << 4))) = p3;
    }
  }

  const int w = tid >> 6;
  const int l = tid & 63;
  const int lr = l & 15;
  const int lk = (l >> 4) * 8;
  const char* xb = (const char*)xs;
  const char* bb = (const char*)bs;
  const int arow = w * 16 + lr;

  for (int rt = blockIdx.x; rt < NTILES; rt += GEMM_BLOCKS) {
    const int r0 = rt * 64;
    __syncthreads();   // B ready (1st iter) / previous iteration's xs reads complete
    {
      char* base = (char*)xs;
#pragma unroll
      for (int i = 0; i < 8; ++i) {
        int f4 = i * 256 + tid;
        int row = f4 >> 5;
        int kq = (f4 & 31) * 4;
        int gr = r0 + row;
        float4 v = make_float4(0.f, 0.f, 0.f, 0.f);
        if (gr < NN) v = *(const float4*)(x + (size_t)gr * IN_F + kq);
        uint lo = (uint)f2bf(v.x) | ((uint)f2bf(v.y) << 16);
        uint hi = (uint)f2bf(v.z) | ((uint)f2bf(v.w) << 16);
        uint off = (uint)((row * 256 + kq * 2) ^ ((row & 7) << 4));
        *(uint2*)(base + off) = make_uint2(lo, hi);
      }
    }
    __syncthreads();

    f32x4 acc[8];
#pragma unroll
    for (int i = 0; i < 8; ++i) acc[i] = (f32x4){0.f, 0.f, 0.f, 0.f};

#pragma unroll
    for (int ks = 0; ks < 4; ++ks) {
      const int kbase = ks * 32 + lk;
      short8 af = *(const short8*)(xb + ((arow * 256 + kbase * 2) ^ ((arow & 7) << 4)));
#pragma unroll
      for (int ct = 0; ct < 8; ++ct) {
        const int c = ct * 16 + lr;
        short8 bfr = *(const short8*)(bb + ((c * 256 + kbase * 2) ^ ((c & 7) << 4)));
        acc[ct] = __builtin_amdgcn_mfma_f32_16x16x32_bf16(af, bfr, acc[ct], 0, 0, 0);
      }
    }

    const int rb = r0 + w * 16;
#pragma unroll
    for (int ct = 0; ct < 8; ++ct) {
#pragma unroll
      for (int r = 0; r < 4; ++r) {
        int gr = rb + (l >> 4) * 4 + r;
        if (gr < NN) {
          if (ct < 4) h[(size_t)gr * HC + ct * 16 + lr] = f2bf(acc[ct][r]);
          else        res[(size_t)gr * HC + (ct - 4) * 16 + lr] = f2bf(acc[ct][r]);
        }
      }
    }

    float myS[4] = {0.f, 0.f, 0.f, 0.f};
    float myD[4] = {0.f, 0.f, 0.f, 0.f};
#pragma unroll
    for (int ct = 0; ct < 4; ++ct) {
      float asv = a_src[ct * 16 + lr];
      float adv = a_dst[ct * 16 + lr];
#pragma unroll
      for (int r = 0; r < 4; ++r) {
        float ps = acc[ct][r] * asv;
        float pd = acc[ct][r] * adv;
        ps += __shfl_xor(ps, 1); ps += __shfl_xor(ps, 2); ps += __shfl_xor(ps, 4); ps += __shfl_xor(ps, 8);
        pd += __shfl_xor(pd, 1); pd += __shfl_xor(pd, 2); pd += __shfl_xor(pd, 4); pd += __shfl_xor(pd, 8);
        if (lr == ct) { myS[r] = ps; myD[r] = pd; }
      }
    }
    if (lr < 4) {
#pragma unroll
      for (int r = 0; r < 4; ++r) {
        int gr = rb + (l >> 4) * 4 + r;
        if (gr < NN) {
          al_s[gr * 4 + lr] = myS[r];
          al_d[gr * 4 + lr] = myD[r];
        }
      }
    }
  }
}

// ---------------- Kernel 2: per-block bucket histogram, int4-vectorized ----------------
__global__ __launch_bounds__(256) void histB_kernel(const int* __restrict__ dst,
                                                    int* __restrict__ histmat,
                                                    float* __restrict__ sums) {
  __shared__ int lh[NBKT];
  const int tid = threadIdx.x;
  if (blockIdx.x == 0 && tid < 32)
    ((float4*)sums)[tid] = make_float4(0.f, 0.f, 0.f, 0.f);   // 128 floats
  for (int i = tid; i < NBKT; i += 256) lh[i] = 0;
  __syncthreads();
  const int4* d4 = (const int4*)(dst + blockIdx.x * EPB2);
  for (int p = tid; p < EPB2 / 4; p += 256) {
    int4 d = d4[p];
    atomicAdd(&lh[d.x >> 8], 1);
    atomicAdd(&lh[d.y >> 8], 1);
    atomicAdd(&lh[d.z >> 8], 1);
    atomicAdd(&lh[d.w >> 8], 1);
  }
  __syncthreads();
  for (int i = tid; i < NBKT; i += 256) histmat[i * NBLKS + blockIdx.x] = lh[i];
}

// ---------------- Kernel 3: place edges into bucket-sorted pairs (scanB folded in) -----
// Each block re-derives its cursor column: thread i<196 serially sums row i of histmat
// (rowsum, L2-hot) and its prefix below column b (colpart); block-scan of rowsums gives
// the bucket base; cur[i] = excl[i] + colpart[i]. Block 0 (colpart==0) also emits
// bucket_base for bscatter. Pure integer work -> bitwise-identical pairs/col layout.
__global__ __launch_bounds__(256) void placeB_kernel(const int* __restrict__ src,
                                                     const int* __restrict__ dst,
                                                     const int* __restrict__ histmat,
                                                     uint* __restrict__ pairs,
                                                     int* __restrict__ bucket_base) {
  __shared__ int cur[NBKT];
  __shared__ int ws2[4];
  const int b = blockIdx.x;
  const int tid = threadIdx.x;
  const int lane = tid & 63;
  const int wv = tid >> 6;

  int rowsum = 0, colpart = 0;
  if (tid < NBKT) {
    const int* row = histmat + tid * NBLKS;
    for (int c = 0; c < NBLKS; ++c) {
      int v = row[c];
      rowsum += v;
      colpart += (c < b) ? v : 0;
    }
  }
  // exclusive scan of rowsums over tid (rowsum==0 for tid>=NBKT)
  int incl = rowsum;
#pragma unroll
  for (int off = 1; off < 64; off <<= 1) {
    int t = __shfl_up(incl, off);
    if (lane >= off) incl += t;
  }
  if (lane == 63) ws2[wv] = incl;
  __syncthreads();
  int woff = 0;
  for (int w = 0; w < wv; ++w) woff += ws2[w];
  const int excl = woff + incl - rowsum;
  if (tid < NBKT) {
    cur[tid] = excl + colpart;
    if (b == 0) bucket_base[tid] = excl;
  }
  if (b == 0 && tid == 0) bucket_base[NBKT] = EE;
  __syncthreads();

  const int4* s4 = (const int4*)(src + b * EPB2);
  const int4* d4 = (const int4*)(dst + b * EPB2);
  for (int p = tid; p < EPB2 / 4; p += 256) {
    int4 d = d4[p];
    int4 s = s4[p];
    int q;
    q = atomicAdd(&cur[d.x >> 8], 1); pairs[q] = ((uint)(d.x & 255) << 16) | (uint)s.x;
    q = atomicAdd(&cur[d.y >> 8], 1); pairs[q] = ((uint)(d.y & 255) << 16) | (uint)s.y;
    q = atomicAdd(&cur[d.z >> 8], 1); pairs[q] = ((uint)(d.z & 255) << 16) | (uint)s.z;
    q = atomicAdd(&cur[d.w >> 8], 1); pairs[q] = ((uint)(d.w & 255) << 16) | (uint)s.w;
  }
}

// ---------------- Kernel 4: fine scatter; derives row_ptr locally ----------------
__global__ __launch_bounds__(256) void bscatter_kernel(const uint* __restrict__ pairs,
                                                       const int* __restrict__ bucket_base,
                                                       int* __restrict__ row_ptr,
                                                       int* __restrict__ col) {
  __shared__ int cnt[256];
  __shared__ int wsum[4];
  const int b = blockIdx.x;
  const int tid = threadIdx.x;
  cnt[tid] = 0;
  __syncthreads();
  const int lo = bucket_base[b];
  const int hi = bucket_base[b + 1];
  for (int i = lo + tid; i < hi; i += 256)
    atomicAdd(&cnt[(pairs[i] >> 16) & 255], 1);
  __syncthreads();
  const int lane = tid & 63;
  const int wv = tid >> 6;
  const int v = cnt[tid];
  int incl = v;
#pragma unroll
  for (int off = 1; off < 64; off <<= 1) {
    int t = __shfl_up(incl, off);
    if (lane >= off) incl += t;
  }
  if (lane == 63) wsum[wv] = incl;
  __syncthreads();
  int woff = 0;
  for (int w = 0; w < wv; ++w) woff += wsum[w];
  const int excl = lo + woff + incl - v;
  __syncthreads();
  cnt[tid] = excl;                     // reuse as cursor
  const int node = (b << 8) + tid;
  if (node < NN) row_ptr[node] = excl;
  if (b == NBKT - 1 && tid == 255) row_ptr[NN] = EE;
  __syncthreads();
  for (int i = lo + tid; i < hi; i += 256) {
    uint u = pairs[i];
    int d = (u >> 16) & 255;
    int p = atomicAdd(&cnt[d], 1);
    col[p] = (int)(u & 0xFFFFu);
  }
}

// ---------------- Kernel 5: per-node aggregate (coop exp + flat batched gathers) -------
// EXACT R14 structure: one wave per node, 12500 blocks.
__global__ __launch_bounds__(256) void node_kernel(
    const ushort* __restrict__ h, const float* __restrict__ al_s, const float* __restrict__ al_d,
    const int* __restrict__ row_ptr, const int* __restrict__ col,
    ushort* __restrict__ out_pre) {
  const int node = blockIdx.x * 4 + (threadIdx.x >> 6);
  const int lane = threadIdx.x & 63;
  const int head = lane >> 4;       // phase-B head (channel group)
  const int hdA = lane & 3;         // phase-A head
  const int elA = lane >> 2;        // phase-A edge slot (0..15)

  const float aldB = al_d[(uint)node * 4u + head];
  const float aldA = al_d[(uint)node * 4u + hdA];

  float e0 = al_s[(uint)node * 4u + head] + aldB;   // self loop
  e0 = e0 > 0.f ? e0 : NEG_SLOPE * e0;
  float m = __expf(e0);
  float denom = m;
  float acc = m * bf2f(h[((uint)node << 6) + lane]);

  const int beg = row_ptr[node];
  const int end = row_ptr[node + 1];
  for (int idx = beg; idx < end; idx += 16) {
    // phase A: one (edge, head) numerator per lane; 0 for tail slots
    const int j = idx + elA;
    const uint sA = (uint)col[j < end ? j : beg];
    float ee = al_s[sA * 4u + hdA] + aldA;
    ee = ee > 0.f ? ee : NEG_SLOPE * ee;
    const float mmA = (j < end) ? __expf(ee) : 0.f;
    // phase B: flat, branch-free
    uint ss[16];
#pragma unroll
    for (int e = 0; e < 16; ++e) ss[e] = (uint)__shfl((int)sA, e * 4);
    float hv[16];
#pragma unroll
    for (int e = 0; e < 16; ++e) hv[e] = bf2f(h[(ss[e] << 6) + lane]);
    float mm[16];
#pragma unroll
    for (int e = 0; e < 16; ++e) mm[e] = __shfl(mmA, e * 4 + head);
#pragma unroll
    for (int e = 0; e < 16; ++e) {
      denom += mm[e];
      acc = fmaf(mm[e], hv[e], acc);
    }
  }
  out_pre[((uint)node << 6) + lane] = f2bf(acc / denom);
}

// ---------------- Kernel 6: BN statistics (bf16 in, uint-paired loads) ----------------
__global__ __launch_bounds__(256) void stats_kernel(const uint* __restrict__ out_pre_u,
                                                    float* __restrict__ sums) {
  const int tid = threadIdx.x;
  const int c2 = tid & 31;             // channel pair: channels 2*c2, 2*c2+1
  const int rg = tid >> 5;             // 8 row groups
  float s0 = 0.f, s1 = 0.f, q0 = 0.f, q1 = 0.f;
  for (int r = blockIdx.x * 8 + rg; r < NN; r += gridDim.x * 8) {
    uint u = out_pre_u[((uint)r << 5) + c2];
    float v0 = bf2f((ushort)(u & 0xFFFFu));
    float v1 = bf2f((ushort)(u >> 16));
    s0 += v0; s1 += v1;
    q0 = fmaf(v0, v0, q0); q1 = fmaf(v1, v1, q1);
  }
  __shared__ float l0[256], l1[256], l2[256], l3[256];
  l0[tid] = s0; l1[tid] = s1; l2[tid] = q0; l3[tid] = q1;
  __syncthreads();
  if (tid < 32) {
    float a0 = 0.f, a1 = 0.f, a2 = 0.f, a3 = 0.f;
#pragma unroll
    for (int g = 0; g < 8; ++g) {
      a0 += l0[g * 32 + tid]; a1 += l1[g * 32 + tid];
      a2 += l2[g * 32 + tid]; a3 += l3[g * 32 + tid];
    }
    atomicAdd(&sums[tid * 2], a0);
    atomicAdd(&sums[tid * 2 + 1], a1);
    atomicAdd(&sums[64 + tid * 2], a2);
    atomicAdd(&sums[64 + tid * 2 + 1], a3);
  }
}

// ---------------- Kernel 7: BN + ELU + residual (4 elems/thread) ----------------
__global__ __launch_bounds__(256) void final_kernel(
    const uint* __restrict__ out_pre_u, const uint* __restrict__ res_u,
    const float* __restrict__ sums, const float* __restrict__ gamma,
    const float* __restrict__ beta, float* __restrict__ out) {
  const int i = blockIdx.x * 256 + threadIdx.x;     // quad index; 3125*256 == NN*HC/4
  const int c4 = (i & 15) * 4;
  const float inv_n = 1.0f / (float)NN;
  uint2 op = *(const uint2*)&out_pre_u[(size_t)i * 2];
  uint2 rs = *(const uint2*)&res_u[(size_t)i * 2];
  float4 g4 = *(const float4*)&gamma[c4];
  float4 b4 = *(const float4*)&beta[c4];
  float pv[4] = { bf2f((ushort)(op.x & 0xFFFFu)), bf2f((ushort)(op.x >> 16)),
                  bf2f((ushort)(op.y & 0xFFFFu)), bf2f((ushort)(op.y >> 16)) };
  float rv[4] = { bf2f((ushort)(rs.x & 0xFFFFu)), bf2f((ushort)(rs.x >> 16)),
                  bf2f((ushort)(rs.y & 0xFFFFu)), bf2f((ushort)(rs.y >> 16)) };
  float gg[4] = { g4.x, g4.y, g4.z, g4.w };
  float bb[4] = { b4.x, b4.y, b4.z, b4.w };
  float4 o;
  float* po = &o.x;
#pragma unroll
  for (int k = 0; k < 4; ++k) {
    int c = c4 + k;
    float mu = sums[c] * inv_n;
    float var = sums[64 + c] * inv_n - mu * mu;
    float rinv = rsqrtf(var + BN_EPS);
    float v = (pv[k] - mu) * rinv * gg[k] + bb[k];
    v = v > 0.f ? v : (__expf(v) - 1.0f);
    po[k] = v + rv[k];
  }
  *(float4*)&out[(size_t)i * 4] = o;
}

extern "C" void kernel_launch(void* const* d_in, const int* in_sizes, int n_in,
                              void* d_out, int out_size, void* d_ws, size_t ws_size,
                              hipStream_t stream) {
  const float* x     = (const float*)d_in[0];
  const int*   ei    = (const int*)d_in[1];     // [2,E]: src = ei, dst = ei+E
  const float* W     = (const float*)d_in[2];
  const float* a_src = (const float*)d_in[3];
  const float* a_dst = (const float*)d_in[4];
  // d_in[5] = bias: cancels exactly through BatchNorm mean-subtraction -> unused
  const float* gamma = (const float*)d_in[6];
  const float* beta  = (const float*)d_in[7];
  const float* Wres  = (const float*)d_in[8];
  float* out = (float*)d_out;

  char* ws = (char*)d_ws;
  ushort* h        = (ushort*)ws; ws += (size_t)NN * HC * 2;   // bf16 h
  ushort* resb     = (ushort*)ws; ws += (size_t)NN * HC * 2;   // bf16 res
  ushort* out_pre  = (ushort*)ws; ws += (size_t)NN * HC * 2;   // bf16 out_pre
  float* al_s      = (float*)ws;  ws += (size_t)NN * 4 * 4;
  float* al_d      = (float*)ws;  ws += (size_t)NN * 4 * 4;
  float* sums      = (float*)ws;  ws += 128 * 4;               // [0:64]=sum, [64:128]=sumsq
  int*   row_ptr   = (int*)ws;    ws += (size_t)(NN + 1) * 4;
  int*   histmat   = (int*)ws;    ws += (size_t)TOTH * 4;      // [bucket][block]
  int*   bucket_base = (int*)ws;  ws += (NBKT + 1) * 4;
  uint*  pairs     = (uint*)ws;   ws += (size_t)EE * 4;
  int*   col       = (int*)ws;    ws += (size_t)EE * 4;

  gemm_mfma_kernel<<<GEMM_BLOCKS, 256, 0, stream>>>(x, W, Wres, a_src, a_dst,
                                                    h, resb, al_s, al_d);
  histB_kernel<<<NBLKS, 256, 0, stream>>>(ei + EE, histmat, sums);
  placeB_kernel<<<NBLKS, 256, 0, stream>>>(ei, ei + EE, histmat, pairs, bucket_base);
  bscatter_kernel<<<NBKT, 256, 0, stream>>>(pairs, bucket_base, row_ptr, col);
  node_kernel<<<NN / 4, 256, 0, stream>>>(h, al_s, al_d, row_ptr, col, out_pre);
  stats_kernel<<<256, 256, 0, stream>>>((const uint*)out_pre, sums);
  final_kernel<<<NN * HC / 1024, 256, 0, stream>>>((const uint*)out_pre, (const uint*)resb,
                                                   sums, gamma, beta, out);
}

// Round 20
// 102.150 us; speedup vs baseline: 1.4430x; 1.0300x over previous
//
#include <hip/hip_runtime.h>
#include <hip/hip_bf16.h>

#define NN 50000
#define EE 800000
#define IN_F 128
#define HC 64
#define NEG_SLOPE 0.2f
#define BN_EPS 1e-5f

#define NBKT 196          // buckets of 256 nodes: dst>>8 (max 49999>>8 = 195)
#define NBLKS 200         // sort chunks (200 x 4000 = 800000)
#define EPB2 (EE / NBLKS) // 4000 edges per sort chunk
#define TOTH (NBKT * NBLKS)  // 39200
#define GEMM_BLOCKS 391   // persistent gemm: exactly 2 tiles/block (391*2 = 782)
#define NTILES ((NN + 63) / 64)  // 782 row tiles

typedef __attribute__((ext_vector_type(8))) short short8;
typedef __attribute__((ext_vector_type(4))) float f32x4;

__device__ __forceinline__ ushort f2bf(float f) {
  uint u = __float_as_uint(f);
  uint r = u + 0x7FFF + ((u >> 16) & 1);   // RNE
  return (ushort)(r >> 16);
}
__device__ __forceinline__ float bf2f(ushort u) {
  return __uint_as_float(((uint)u) << 16);
}

// ---------------- Kernel 1: persistent MFMA bf16 GEMM + fused edge histogram ----------
// B=[W|Wres] (64KB bf16, swizzled) staged ONCE per block; exactly 2 row tiles/block.
// Tail: blocks 0..NBLKS-1 reuse the bs LDS as a 196-counter histogram and process their
// 4000-edge chunk (exact histB body) -> one fewer launch + gap.
__global__ __launch_bounds__(256) void gemm_mfma_kernel(
    const float* __restrict__ x, const float* __restrict__ W, const float* __restrict__ Wres,
    const float* __restrict__ a_src, const float* __restrict__ a_dst,
    const int* __restrict__ dstv, ushort* __restrict__ h, ushort* __restrict__ res,
    float* __restrict__ al_s, float* __restrict__ al_d,
    int* __restrict__ histmat, float* __restrict__ sums) {
  __shared__ ushort bs[128 * 128];   // [col][k] bf16, swizzled: byte ^= (col&7)<<4
  __shared__ ushort xs[64 * 128];    // [row][k] bf16, swizzled: byte ^= (row&7)<<4

  const int tid = threadIdx.x;

  // ---- stage B once ----
  {
    const int c4 = (tid & 31) * 4;
    const int kb = (tid >> 5) * 16;
    const float* src0 = (c4 < HC) ? (W + c4) : (Wres + (c4 - HC));
    char* base = (char*)bs;
#pragma unroll
    for (int j = 0; j < 8; ++j) {
      int k0 = kb + j * 2;
      float4 fa = *(const float4*)(src0 + (size_t)k0 * HC);
      float4 fb = *(const float4*)(src0 + (size_t)(k0 + 1) * HC);
      uint p0 = (uint)f2bf(fa.x) | ((uint)f2bf(fb.x) << 16);
      uint p1 = (uint)f2bf(fa.y) | ((uint)f2bf(fb.y) << 16);
      uint p2 = (uint)f2bf(fa.z) | ((uint)f2bf(fb.z) << 16);
      uint p3 = (uint)f2bf(fa.w) | ((uint)f2bf(fb.w) << 16);
      *(uint*)(base + (((c4 + 0) * 256 + k0 * 2) ^ (((c4 + 0) & 7) << 4))) = p0;
      *(uint*)(base + (((c4 + 1) * 256 + k0 * 2) ^ (((c4 + 1) & 7) << 4))) = p1;
      *(uint*)(base + (((c4 + 2) * 256 + k0 * 2) ^ (((c4 + 2) & 7) << 4))) = p2;
      *(uint*)(base + (((c4 + 3) * 256 + k0 * 2) ^ (((c4 + 3) & 7) << 4))) = p3;
    }
  }

  const int w = tid >> 6;
  const int l = tid & 63;
  const int lr = l & 15;
  const int lk = (l >> 4) * 8;
  const char* xb = (const char*)xs;
  const char* bb = (const char*)bs;
  const int arow = w * 16 + lr;

  for (int rt = blockIdx.x; rt < NTILES; rt += GEMM_BLOCKS) {
    const int r0 = rt * 64;
    __syncthreads();   // B ready (1st iter) / previous iteration's xs reads complete
    {
      char* base = (char*)xs;
#pragma unroll
      for (int i = 0; i < 8; ++i) {
        int f4 = i * 256 + tid;
        int row = f4 >> 5;
        int kq = (f4 & 31) * 4;
        int gr = r0 + row;
        float4 v = make_float4(0.f, 0.f, 0.f, 0.f);
        if (gr < NN) v = *(const float4*)(x + (size_t)gr * IN_F + kq);
        uint lo = (uint)f2bf(v.x) | ((uint)f2bf(v.y) << 16);
        uint hi = (uint)f2bf(v.z) | ((uint)f2bf(v.w) << 16);
        uint off = (uint)((row * 256 + kq * 2) ^ ((row & 7) << 4));
        *(uint2*)(base + off) = make_uint2(lo, hi);
      }
    }
    __syncthreads();

    f32x4 acc[8];
#pragma unroll
    for (int i = 0; i < 8; ++i) acc[i] = (f32x4){0.f, 0.f, 0.f, 0.f};

#pragma unroll
    for (int ks = 0; ks < 4; ++ks) {
      const int kbase = ks * 32 + lk;
      short8 af = *(const short8*)(xb + ((arow * 256 + kbase * 2) ^ ((arow & 7) << 4)));
#pragma unroll
      for (int ct = 0; ct < 8; ++ct) {
        const int c = ct * 16 + lr;
        short8 bfr = *(const short8*)(bb + ((c * 256 + kbase * 2) ^ ((c & 7) << 4)));
        acc[ct] = __builtin_amdgcn_mfma_f32_16x16x32_bf16(af, bfr, acc[ct], 0, 0, 0);
      }
    }

    const int rb = r0 + w * 16;
#pragma unroll
    for (int ct = 0; ct < 8; ++ct) {
#pragma unroll
      for (int r = 0; r < 4; ++r) {
        int gr = rb + (l >> 4) * 4 + r;
        if (gr < NN) {
          if (ct < 4) h[(size_t)gr * HC + ct * 16 + lr] = f2bf(acc[ct][r]);
          else        res[(size_t)gr * HC + (ct - 4) * 16 + lr] = f2bf(acc[ct][r]);
        }
      }
    }

    float myS[4] = {0.f, 0.f, 0.f, 0.f};
    float myD[4] = {0.f, 0.f, 0.f, 0.f};
#pragma unroll
    for (int ct = 0; ct < 4; ++ct) {
      float asv = a_src[ct * 16 + lr];
      float adv = a_dst[ct * 16 + lr];
#pragma unroll
      for (int r = 0; r < 4; ++r) {
        float ps = acc[ct][r] * asv;
        float pd = acc[ct][r] * adv;
        ps += __shfl_xor(ps, 1); ps += __shfl_xor(ps, 2); ps += __shfl_xor(ps, 4); ps += __shfl_xor(ps, 8);
        pd += __shfl_xor(pd, 1); pd += __shfl_xor(pd, 2); pd += __shfl_xor(pd, 4); pd += __shfl_xor(pd, 8);
        if (lr == ct) { myS[r] = ps; myD[r] = pd; }
      }
    }
    if (lr < 4) {
#pragma unroll
      for (int r = 0; r < 4; ++r) {
        int gr = rb + (l >> 4) * 4 + r;
        if (gr < NN) {
          al_s[gr * 4 + lr] = myS[r];
          al_d[gr * 4 + lr] = myD[r];
        }
      }
    }
  }

  // ---- fused histB tail: blocks 0..NBLKS-1 histogram their edge chunk ----
  if (blockIdx.x < NBLKS) {
    __syncthreads();                      // main-loop LDS reads complete
    int* lh = (int*)bs;                   // reuse B staging LDS
    if (blockIdx.x == 0 && tid < 32)
      ((float4*)sums)[tid] = make_float4(0.f, 0.f, 0.f, 0.f);   // zero BN sums
    for (int i = tid; i < NBKT; i += 256) lh[i] = 0;
    __syncthreads();
    const int4* d4 = (const int4*)(dstv + blockIdx.x * EPB2);
    for (int p = tid; p < EPB2 / 4; p += 256) {
      int4 d = d4[p];
      atomicAdd(&lh[d.x >> 8], 1);
      atomicAdd(&lh[d.y >> 8], 1);
      atomicAdd(&lh[d.z >> 8], 1);
      atomicAdd(&lh[d.w >> 8], 1);
    }
    __syncthreads();
    for (int i = tid; i < NBKT; i += 256) histmat[i * NBLKS + blockIdx.x] = lh[i];
  }
}

// ---------------- Kernel 2: place edges into bucket-sorted pairs (scanB folded in) -----
__global__ __launch_bounds__(256) void placeB_kernel(const int* __restrict__ src,
                                                     const int* __restrict__ dst,
                                                     const int* __restrict__ histmat,
                                                     uint* __restrict__ pairs,
                                                     int* __restrict__ bucket_base) {
  __shared__ int cur[NBKT];
  __shared__ int ws2[4];
  const int b = blockIdx.x;
  const int tid = threadIdx.x;
  const int lane = tid & 63;
  const int wv = tid >> 6;

  int rowsum = 0, colpart = 0;
  if (tid < NBKT) {
    const int* row = histmat + tid * NBLKS;
    for (int c = 0; c < NBLKS; ++c) {
      int v = row[c];
      rowsum += v;
      colpart += (c < b) ? v : 0;
    }
  }
  int incl = rowsum;
#pragma unroll
  for (int off = 1; off < 64; off <<= 1) {
    int t = __shfl_up(incl, off);
    if (lane >= off) incl += t;
  }
  if (lane == 63) ws2[wv] = incl;
  __syncthreads();
  int woff = 0;
  for (int w = 0; w < wv; ++w) woff += ws2[w];
  const int excl = woff + incl - rowsum;
  if (tid < NBKT) {
    cur[tid] = excl + colpart;
    if (b == 0) bucket_base[tid] = excl;
  }
  if (b == 0 && tid == 0) bucket_base[NBKT] = EE;
  __syncthreads();

  const int4* s4 = (const int4*)(src + b * EPB2);
  const int4* d4 = (const int4*)(dst + b * EPB2);
  for (int p = tid; p < EPB2 / 4; p += 256) {
    int4 d = d4[p];
    int4 s = s4[p];
    int q;
    q = atomicAdd(&cur[d.x >> 8], 1); pairs[q] = ((uint)(d.x & 255) << 16) | (uint)s.x;
    q = atomicAdd(&cur[d.y >> 8], 1); pairs[q] = ((uint)(d.y & 255) << 16) | (uint)s.y;
    q = atomicAdd(&cur[d.z >> 8], 1); pairs[q] = ((uint)(d.z & 255) << 16) | (uint)s.z;
    q = atomicAdd(&cur[d.w >> 8], 1); pairs[q] = ((uint)(d.w & 255) << 16) | (uint)s.w;
  }
}

// ---------------- Kernel 3: fine scatter; derives row_ptr locally ----------------
__global__ __launch_bounds__(256) void bscatter_kernel(const uint* __restrict__ pairs,
                                                       const int* __restrict__ bucket_base,
                                                       int* __restrict__ row_ptr,
                                                       int* __restrict__ col) {
  __shared__ int cnt[256];
  __shared__ int wsum[4];
  const int b = blockIdx.x;
  const int tid = threadIdx.x;
  cnt[tid] = 0;
  __syncthreads();
  const int lo = bucket_base[b];
  const int hi = bucket_base[b + 1];
  for (int i = lo + tid; i < hi; i += 256)
    atomicAdd(&cnt[(pairs[i] >> 16) & 255], 1);
  __syncthreads();
  const int lane = tid & 63;
  const int wv = tid >> 6;
  const int v = cnt[tid];
  int incl = v;
#pragma unroll
  for (int off = 1; off < 64; off <<= 1) {
    int t = __shfl_up(incl, off);
    if (lane >= off) incl += t;
  }
  if (lane == 63) wsum[wv] = incl;
  __syncthreads();
  int woff = 0;
  for (int w = 0; w < wv; ++w) woff += wsum[w];
  const int excl = lo + woff + incl - v;
  __syncthreads();
  cnt[tid] = excl;                     // reuse as cursor
  const int node = (b << 8) + tid;
  if (node < NN) row_ptr[node] = excl;
  if (b == NBKT - 1 && tid == 255) row_ptr[NN] = EE;
  __syncthreads();
  for (int i = lo + tid; i < hi; i += 256) {
    uint u = pairs[i];
    int d = (u >> 16) & 255;
    int p = atomicAdd(&cnt[d], 1);
    col[p] = (int)(u & 0xFFFFu);
  }
}

// ---------------- Kernel 4: per-node aggregate (coop exp + flat batched gathers) -------
// EXACT R14 structure: one wave per node, 12500 blocks.
__global__ __launch_bounds__(256) void node_kernel(
    const ushort* __restrict__ h, const float* __restrict__ al_s, const float* __restrict__ al_d,
    const int* __restrict__ row_ptr, const int* __restrict__ col,
    ushort* __restrict__ out_pre) {
  const int node = blockIdx.x * 4 + (threadIdx.x >> 6);
  const int lane = threadIdx.x & 63;
  const int head = lane >> 4;       // phase-B head (channel group)
  const int hdA = lane & 3;         // phase-A head
  const int elA = lane >> 2;        // phase-A edge slot (0..15)

  const float aldB = al_d[(uint)node * 4u + head];
  const float aldA = al_d[(uint)node * 4u + hdA];

  float e0 = al_s[(uint)node * 4u + head] + aldB;   // self loop
  e0 = e0 > 0.f ? e0 : NEG_SLOPE * e0;
  float m = __expf(e0);
  float denom = m;
  float acc = m * bf2f(h[((uint)node << 6) + lane]);

  const int beg = row_ptr[node];
  const int end = row_ptr[node + 1];
  for (int idx = beg; idx < end; idx += 16) {
    // phase A: one (edge, head) numerator per lane; 0 for tail slots
    const int j = idx + elA;
    const uint sA = (uint)col[j < end ? j : beg];
    float ee = al_s[sA * 4u + hdA] + aldA;
    ee = ee > 0.f ? ee : NEG_SLOPE * ee;
    const float mmA = (j < end) ? __expf(ee) : 0.f;
    // phase B: flat, branch-free
    uint ss[16];
#pragma unroll
    for (int e = 0; e < 16; ++e) ss[e] = (uint)__shfl((int)sA, e * 4);
    float hv[16];
#pragma unroll
    for (int e = 0; e < 16; ++e) hv[e] = bf2f(h[(ss[e] << 6) + lane]);
    float mm[16];
#pragma unroll
    for (int e = 0; e < 16; ++e) mm[e] = __shfl(mmA, e * 4 + head);
#pragma unroll
    for (int e = 0; e < 16; ++e) {
      denom += mm[e];
      acc = fmaf(mm[e], hv[e], acc);
    }
  }
  out_pre[((uint)node << 6) + lane] = f2bf(acc / denom);
}

// ---------------- Kernel 5: BN statistics (bf16 in, uint-paired loads) ----------------
__global__ __launch_bounds__(256) void stats_kernel(const uint* __restrict__ out_pre_u,
                                                    float* __restrict__ sums) {
  const int tid = threadIdx.x;
  const int c2 = tid & 31;             // channel pair: channels 2*c2, 2*c2+1
  const int rg = tid >> 5;             // 8 row groups
  float s0 = 0.f, s1 = 0.f, q0 = 0.f, q1 = 0.f;
  for (int r = blockIdx.x * 8 + rg; r < NN; r += gridDim.x * 8) {
    uint u = out_pre_u[((uint)r << 5) + c2];
    float v0 = bf2f((ushort)(u & 0xFFFFu));
    float v1 = bf2f((ushort)(u >> 16));
    s0 += v0; s1 += v1;
    q0 = fmaf(v0, v0, q0); q1 = fmaf(v1, v1, q1);
  }
  __shared__ float l0[256], l1[256], l2[256], l3[256];
  l0[tid] = s0; l1[tid] = s1; l2[tid] = q0; l3[tid] = q1;
  __syncthreads();
  if (tid < 32) {
    float a0 = 0.f, a1 = 0.f, a2 = 0.f, a3 = 0.f;
#pragma unroll
    for (int g = 0; g < 8; ++g) {
      a0 += l0[g * 32 + tid]; a1 += l1[g * 32 + tid];
      a2 += l2[g * 32 + tid]; a3 += l3[g * 32 + tid];
    }
    atomicAdd(&sums[tid * 2], a0);
    atomicAdd(&sums[tid * 2 + 1], a1);
    atomicAdd(&sums[64 + tid * 2], a2);
    atomicAdd(&sums[64 + tid * 2 + 1], a3);
  }
}

// ---------------- Kernel 6: BN + ELU + residual (4 elems/thread) ----------------
__global__ __launch_bounds__(256) void final_kernel(
    const uint* __restrict__ out_pre_u, const uint* __restrict__ res_u,
    const float* __restrict__ sums, const float* __restrict__ gamma,
    const float* __restrict__ beta, float* __restrict__ out) {
  const int i = blockIdx.x * 256 + threadIdx.x;     // quad index; 3125*256 == NN*HC/4
  const int c4 = (i & 15) * 4;
  const float inv_n = 1.0f / (float)NN;
  uint2 op = *(const uint2*)&out_pre_u[(size_t)i * 2];
  uint2 rs = *(const uint2*)&res_u[(size_t)i * 2];
  float4 g4 = *(const float4*)&gamma[c4];
  float4 b4 = *(const float4*)&beta[c4];
  float pv[4] = { bf2f((ushort)(op.x & 0xFFFFu)), bf2f((ushort)(op.x >> 16)),
                  bf2f((ushort)(op.y & 0xFFFFu)), bf2f((ushort)(op.y >> 16)) };
  float rv[4] = { bf2f((ushort)(rs.x & 0xFFFFu)), bf2f((ushort)(rs.x >> 16)),
                  bf2f((ushort)(rs.y & 0xFFFFu)), bf2f((ushort)(rs.y >> 16)) };
  float gg[4] = { g4.x, g4.y, g4.z, g4.w };
  float bb[4] = { b4.x, b4.y, b4.z, b4.w };
  float4 o;
  float* po = &o.x;
#pragma unroll
  for (int k = 0; k < 4; ++k) {
    int c = c4 + k;
    float mu = sums[c] * inv_n;
    float var = sums[64 + c] * inv_n - mu * mu;
    float rinv = rsqrtf(var + BN_EPS);
    float v = (pv[k] - mu) * rinv * gg[k] + bb[k];
    v = v > 0.f ? v : (__expf(v) - 1.0f);
    po[k] = v + rv[k];
  }
  *(float4*)&out[(size_t)i * 4] = o;
}

extern "C" void kernel_launch(void* const* d_in, const int* in_sizes, int n_in,
                              void* d_out, int out_size, void* d_ws, size_t ws_size,
                              hipStream_t stream) {
  const float* x     = (const float*)d_in[0];
  const int*   ei    = (const int*)d_in[1];     // [2,E]: src = ei, dst = ei+E
  const float* W     = (const float*)d_in[2];
  const float* a_src = (const float*)d_in[3];
  const float* a_dst = (const float*)d_in[4];
  // d_in[5] = bias: cancels exactly through BatchNorm mean-subtraction -> unused
  const float* gamma = (const float*)d_in[6];
  const float* beta  = (const float*)d_in[7];
  const float* Wres  = (const float*)d_in[8];
  float* out = (float*)d_out;

  char* ws = (char*)d_ws;
  ushort* h        = (ushort*)ws; ws += (size_t)NN * HC * 2;   // bf16 h
  ushort* resb     = (ushort*)ws; ws += (size_t)NN * HC * 2;   // bf16 res
  ushort* out_pre  = (ushort*)ws; ws += (size_t)NN * HC * 2;   // bf16 out_pre
  float* al_s      = (float*)ws;  ws += (size_t)NN * 4 * 4;
  float* al_d      = (float*)ws;  ws += (size_t)NN * 4 * 4;
  float* sums      = (float*)ws;  ws += 128 * 4;               // [0:64]=sum, [64:128]=sumsq
  int*   row_ptr   = (int*)ws;    ws += (size_t)(NN + 1) * 4;
  int*   histmat   = (int*)ws;    ws += (size_t)TOTH * 4;      // [bucket][block]
  int*   bucket_base = (int*)ws;  ws += (NBKT + 1) * 4;
  uint*  pairs     = (uint*)ws;   ws += (size_t)EE * 4;
  int*   col       = (int*)ws;    ws += (size_t)EE * 4;

  gemm_mfma_kernel<<<GEMM_BLOCKS, 256, 0, stream>>>(x, W, Wres, a_src, a_dst, ei + EE,
                                                    h, resb, al_s, al_d, histmat, sums);
  placeB_kernel<<<NBLKS, 256, 0, stream>>>(ei, ei + EE, histmat, pairs, bucket_base);
  bscatter_kernel<<<NBKT, 256, 0, stream>>>(pairs, bucket_base, row_ptr, col);
  node_kernel<<<NN / 4, 256, 0, stream>>>(h, al_s, al_d, row_ptr, col, out_pre);
  stats_kernel<<<256, 256, 0, stream>>>((const uint*)out_pre, sums);
  final_kernel<<<NN * HC / 1024, 256, 0, stream>>>((const uint*)out_pre, (const uint*)resb,
                                                   sums, gamma, beta, out);
}